// Round 11
// baseline (865.062 us; speedup 1.0000x reference)
//
#include <hip/hip_runtime.h>
#include <math.h>

#define B_ 8
#define T_ 2048
#define HID_ 256
#define DIN_ 512
#define NST_ 16
#define RANK_ 16
#define NL_ 4
#define NC_ 128  // scan chunks
#define TC_ 16   // steps per chunk

typedef unsigned short u16;
typedef unsigned int u32;
typedef __attribute__((ext_vector_type(8))) short bf16x8;
typedef __attribute__((ext_vector_type(4))) float f32x4;

// single-instruction transcendentals (v_exp_f32 = 2^x)
__device__ __forceinline__ float exp2_i(float x) {
  float r; asm("v_exp_f32 %0, %1" : "=v"(r) : "v"(x)); return r;
}
__device__ __forceinline__ float log2_i(float x) {
  float r; asm("v_log_f32 %0, %1" : "=v"(r) : "v"(x)); return r;
}
__device__ __forceinline__ float rcp_i(float x) {
  float r; asm("v_rcp_f32 %0, %1" : "=v"(r) : "v"(x)); return r;
}
#define LOG2E 1.44269504f
#define LN2   0.69314718f

__device__ __forceinline__ float silu_f(float x) {
  return x * rcp_i(1.f + exp2_i(-LOG2E * x));
}
__device__ __forceinline__ float softplus_f(float x) {
  return (x > 20.f) ? x : LN2 * log2_i(1.f + exp2_i(LOG2E * x));
}

__device__ __forceinline__ u16 f2b(float f) {
  union { float f; unsigned u; } v; v.f = f;
  unsigned r = (v.u + 0x7FFFu + ((v.u >> 16) & 1u)) >> 16;
  return (u16)r;
}
__device__ __forceinline__ float b2f(u16 b) {
  union { unsigned u; float f; } v; v.u = ((unsigned)b) << 16;
  return v.f;
}

__device__ __forceinline__ void async16(const void* g, const void* l) {
  __builtin_amdgcn_global_load_lds(
      (const __attribute__((address_space(1))) unsigned int*)g,
      (__attribute__((address_space(3))) unsigned int*)l, 16, 0, 0);
}

// -------------------- f32 -> bf16 convert --------------------
__global__ __launch_bounds__(256) void f2b_k(const float* __restrict__ s, u16* __restrict__ d, int n)
{
  int i = (blockIdx.x * 256 + threadIdx.x) * 4;
  if (i + 3 < n) {
    float4 v = *(const float4*)(s + i);
    d[i + 0] = f2b(v.x); d[i + 1] = f2b(v.y); d[i + 2] = f2b(v.z); d[i + 3] = f2b(v.w);
  } else {
    for (int k = i; k < n; k++) d[k] = f2b(s[k]);
  }
}

// -------------------- a2 transpose prep: a2t[l][n][d] = -exp(Alog[l][d][n])*log2e
__global__ __launch_bounds__(256) void a2t_k(const float* __restrict__ Alog, float* __restrict__ a2t)
{
  int idx = blockIdx.x * 256 + threadIdx.x;   // NL*16*512 = 32768
  int l = idx >> 13, nd = idx & 8191;
  int n = nd >> 9, d = nd & 511;
  float al = Alog[(size_t)l * 8192 + d * 16 + n];
  a2t[(size_t)l * 8192 + n * 512 + d] = -exp2_i(al * LOG2E) * LOG2E;
}

// -------------------- combined dt+BC weight: wcomb[l][640][512] bf16
// rows 0:512  = dpW @ xpW[0:16]  (merged dt weight)
// rows 512:544 = xpW[16:48]      (B,C rows); rows 544:640 unused
__global__ __launch_bounds__(512) void wmerge_k(
    const float* __restrict__ dpW,   // [NL,512,16]
    const float* __restrict__ xpW,   // [NL,48,512]
    u16* __restrict__ wcomb)         // [NL,640,512] bf16
{
  int n = blockIdx.x, l = blockIdx.y, k = threadIdx.x;
  const float* xp = xpW + (size_t)l * 48 * 512;
  float acc;
  if (n < 512) {
    const float* dp = dpW + ((size_t)l * 512 + n) * 16;
    acc = 0.f;
    #pragma unroll
    for (int r = 0; r < 16; r++) acc += dp[r] * xp[r * 512 + k];
  } else if (n < 544) {
    acc = xp[(size_t)(16 + n - 512) * 512 + k];
  } else {
    acc = 0.f;
  }
  wcomb[((size_t)l * 640 + n) * 512 + k] = f2b(acc);
}

// -------------------- embed + layernorm (register-weight, 32 rows/block) ------
__global__ __launch_bounds__(256) void embed_ln_k(
    const float* __restrict__ tsd, const float* __restrict__ stat, const float* __restrict__ ta,
    const float* __restrict__ tsW, const float* __restrict__ tsb,
    const float* __restrict__ t2vw, const float* __restrict__ t2vb,
    const float* __restrict__ timeW, const float* __restrict__ timeb,
    const float* __restrict__ statW, const float* __restrict__ statb,
    const float* __restrict__ lng, const float* __restrict__ lnb,
    float* __restrict__ hout)
{
  __shared__ float xts[37 * 32];
  __shared__ float tvs[32 * 32];
  __shared__ float outs[32 * 257];
  __shared__ float smu[32], srs[32];
  int blk = blockIdx.x;             // 512 blocks
  int b = blk >> 6, t0 = (blk & 63) * 32;
  int j = threadIdx.x;

  float wts[37], wtv[32], wst[8];
  #pragma unroll
  for (int m = 0; m < 37; m++) wts[m] = tsW[j * 37 + m];
  #pragma unroll
  for (int e = 0; e < 32; e++) wtv[e] = timeW[j * 32 + e];
  #pragma unroll
  for (int s = 0; s < 8; s++) wst[s] = statW[j * 8 + s];
  float biasj = tsb[j] + timeb[j] + statb[j];
  float lngj = lng[j], lnbj = lnb[j];
  float stq[8];
  #pragma unroll
  for (int s = 0; s < 8; s++) stq[s] = stat[b * 8 + s];

  for (int idx = j; idx < 37 * 32; idx += 256) {
    int m = idx >> 5, tt = idx & 31;
    xts[idx] = tsd[((size_t)b * 37 + m) * T_ + t0 + tt];
  }
  {
    int rr = j >> 5, ee = j & 31;
    #pragma unroll
    for (int rp = 0; rp < 4; rp++) {
      int r = rp * 8 + rr;
      float tav = ta[b * T_ + t0 + r];
      float tv = tav * t2vw[ee] + t2vb[ee];
      tvs[r * 32 + ee] = (ee == 0) ? tv : sinf(tv);
    }
  }
  __syncthreads();

  for (int r = 0; r < 32; r++) {
    float acc = biasj;
    #pragma unroll
    for (int m = 0; m < 37; m++) acc += xts[m * 32 + r] * wts[m];
    #pragma unroll
    for (int e = 0; e < 32; e++) acc += tvs[r * 32 + e] * wtv[e];
    #pragma unroll
    for (int s = 0; s < 8; s++) acc += stq[s] * wst[s];
    outs[r * 257 + j] = acc;
  }
  __syncthreads();
  {
    int r = j >> 3, q = j & 7;
    const float* po = &outs[r * 257 + q * 32];
    float s = 0.f, ss = 0.f;
    #pragma unroll
    for (int i = 0; i < 32; i++) { float v = po[i]; s += v; ss += v * v; }
    s += __shfl_down(s, 1, 64); ss += __shfl_down(ss, 1, 64);
    s += __shfl_down(s, 2, 64); ss += __shfl_down(ss, 2, 64);
    s += __shfl_down(s, 4, 64); ss += __shfl_down(ss, 4, 64);
    if (q == 0) {
      float mu = s * (1.f / 256.f);
      smu[r] = mu;
      srs[r] = rsqrtf(ss * (1.f / 256.f) - mu * mu + 1e-12f);
    }
  }
  __syncthreads();
  for (int r = 0; r < 32; r++) {
    float v = outs[r * 257 + j];
    hout[((size_t)(b * T_ + t0 + r)) * HID_ + j] = (v - smu[r]) * srs[r] * lngj + lnbj;
  }
}

// -------------------- rmsnorm (f32 in -> bf16 out, 1 wave/row) ---------------
__global__ __launch_bounds__(256) void rmsnorm_k(
    const float* __restrict__ x, const float* __restrict__ w, u16* __restrict__ o)
{
  int row = blockIdx.x * 4 + (threadIdx.x >> 6);
  int lane = threadIdx.x & 63;
  float4 v = *(const float4*)&x[(size_t)row * HID_ + lane * 4];
  float ss = v.x * v.x + v.y * v.y + v.z * v.z + v.w * v.w;
  #pragma unroll
  for (int ofs = 32; ofs > 0; ofs >>= 1) ss += __shfl_xor(ss, ofs, 64);
  float sc = rsqrtf(ss * (1.f / 256.f) + 1e-5f);
  float4 wv = *(const float4*)&w[lane * 4];
  u16 r[4];
  r[0] = f2b(v.x * sc * wv.x); r[1] = f2b(v.y * sc * wv.y);
  r[2] = f2b(v.z * sc * wv.z); r[3] = f2b(v.w * sc * wv.w);
  *(uint2*)&o[(size_t)row * HID_ + lane * 4] = *(const uint2*)r;
}

// -------------------- bf16 MFMA GEMM: C[M,N] = A @ W^T ----------------------
// MODE 1: f32 out + residual (out_proj)
// MODE 4: bf16 out, dual dest split at col 512 (in_proj -> xi, z)
// MODE 5: dt-pack (cols<512 -> pku) + BC f32 (cols 512:544 -> Cv2 [M,32])
template <int MODE>
__global__ __launch_bounds__(256) void mgemm_k(
    const u16* __restrict__ A, int lda,
    const u16* __restrict__ W, int ldw,
    void* __restrict__ Cv, int ldc,
    int K,
    const float* __restrict__ bias,   // MODE 5: dpb
    const u16* __restrict__ usrc,     // MODE 5: u (xcb)
    void* __restrict__ Cv2)           // MODE 4: z dest; MODE 5: xdbc
{
  __shared__ u16 sA[128 * 64];
  __shared__ u16 sB[128 * 64];
  const int tid = threadIdx.x;
  const int bm = blockIdx.x * 128, bn = blockIdx.y * 128;
  const int w = tid >> 6, l = tid & 63;
  const int wm = (w & 1) * 64, wn = (w >> 1) * 64;
  const int lr = l & 15, lh = l >> 4;

  f32x4 acc[4][4] = {};

  const int srow = tid >> 3;
  const int schunk = tid & 7;

  for (int k0 = 0; k0 < K; k0 += 64) {
    #pragma unroll
    for (int c = 0; c < 4; c++) {
      int row = c * 32 + srow;
      int g = schunk ^ (row & 7);
      async16(A + (size_t)(bm + row) * lda + k0 + g * 8, &sA[c * 2048 + w * 512]);
      async16(W + (size_t)(bn + row) * ldw + k0 + g * 8, &sB[c * 2048 + w * 512]);
    }
    __syncthreads();
    #pragma unroll
    for (int kk = 0; kk < 2; kk++) {
      bf16x8 af[4], bfr[4];
      #pragma unroll
      for (int i = 0; i < 4; i++) {
        int ra = wm + i * 16 + lr;
        int rb = wn + i * 16 + lr;
        int e = kk * 4 + lh;
        af[i]  = *(const bf16x8*)&sA[ra * 64 + ((e ^ (ra & 7)) * 8)];
        bfr[i] = *(const bf16x8*)&sB[rb * 64 + ((e ^ (rb & 7)) * 8)];
      }
      #pragma unroll
      for (int i = 0; i < 4; i++)
        #pragma unroll
        for (int j = 0; j < 4; j++)
          acc[i][j] = __builtin_amdgcn_mfma_f32_16x16x32_bf16(af[i], bfr[j], acc[i][j], 0, 0, 0);
    }
    __syncthreads();
  }

  #pragma unroll
  for (int i = 0; i < 4; i++) {
    int m = bm + wm + i * 16 + lh * 4;
    #pragma unroll
    for (int j = 0; j < 4; j++) {
      int n = bn + wn + j * 16 + lr;
      if (MODE == 4) {
        #pragma unroll
        for (int r = 0; r < 4; r++) {
          u16 v = f2b(acc[i][j][r]);
          if (n < 512) ((u16*)Cv)[(size_t)(m + r) * 512 + n] = v;
          else         ((u16*)Cv2)[(size_t)(m + r) * 512 + (n - 512)] = v;
        }
      } else if (MODE == 5) {
        if (n < 512) {
          float bv = bias[n];
          #pragma unroll
          for (int r = 0; r < 4; r++) {
            float dtv = softplus_f(acc[i][j][r] + bv);
            u32 uu = usrc[(size_t)(m + r) * 512 + n];
            ((u32*)Cv)[(size_t)(m + r) * ldc + n] = (uu << 16) | (u32)f2b(dtv);
          }
        } else if (n < 544) {
          int n2 = n - 512;
          #pragma unroll
          for (int r = 0; r < 4; r++)
            ((float*)Cv2)[(size_t)(m + r) * 32 + n2] = acc[i][j][r];
        }
      } else {
        float* cp = (float*)Cv + (size_t)m * ldc + n;
        #pragma unroll
        for (int r = 0; r < 4; r++) {
          float v = acc[i][j][r];
          if (MODE == 1) v += cp[(size_t)r * ldc];
          cp[(size_t)r * ldc] = v;
        }
      }
    }
  }
}

// -------------------- causal depthwise conv + silu (bf16 in/out, 8 d/thread) --
__global__ __launch_bounds__(256) void conv_silu_k(
    const u16* __restrict__ xib,      // [B*T,512] bf16
    const float* __restrict__ cw,     // [512,4]
    const float* __restrict__ cb,     // [512]
    u16* __restrict__ xcb)            // [B*T,512] bf16
{
  int idx = blockIdx.x * 256 + threadIdx.x;   // ROWS*64 threads
  int row = idx >> 6;
  int t = row & (T_ - 1);
  int d0 = (idx & 63) << 3;

  float acc[8];
  *(float4*)&acc[0] = *(const float4*)&cb[d0];
  *(float4*)&acc[4] = *(const float4*)&cb[d0 + 4];
  float wreg[8][4];
  #pragma unroll
  for (int j = 0; j < 8; j++)
    *(float4*)&wreg[j][0] = *(const float4*)&cw[(d0 + j) * 4];

  #pragma unroll
  for (int k = 0; k < 4; k++) {
    int tt = t + k - 3;
    if (tt >= 0) {
      bf16x8 v = *(const bf16x8*)&xib[(size_t)(row + k - 3) * 512 + d0];
      #pragma unroll
      for (int j = 0; j < 8; j++) acc[j] += wreg[j][k] * b2f((u16)v[j]);
    }
  }
  u16 o[8];
  #pragma unroll
  for (int j = 0; j < 8; j++) o[j] = f2b(silu_f(acc[j]));
  *(bf16x8*)&xcb[(size_t)row * 512 + d0] = *(const bf16x8*)o;
}

// -------------------- chunked selective scan --------------------
// passA: local scan with h_in=0; store hl (bf16) + dtsum (f32)
__global__ __launch_bounds__(512) void scan_passA_k(
    const u32* __restrict__ pku,      // (u,dt) bf16 pair [B*T,512]
    const float* __restrict__ xdbc,   // [M,32]: B cols 0:16
    const float* __restrict__ a2t,    // [16][512]
    u16* __restrict__ chH, float* __restrict__ dts)
{
  __shared__ float sDBC[TC_ * 32];     // 2 KB
  int c = blockIdx.x, b = blockIdx.y, d = threadIdx.x;
  size_t base_row = (size_t)(b * T_ + c * TC_);

  if (d < 128) async16(xdbc + base_row * 32 + d * 4, &sDBC[(d >> 6) * 256]);

  float a2[16], hl[16];
  #pragma unroll
  for (int n = 0; n < 16; n++) { a2[n] = a2t[n * 512 + d]; hl[n] = 0.f; }
  float dtsum = 0.f;
  const u32* pp = pku + base_row * 512 + d;
  u32 pk = pp[0];
  __syncthreads();

  #pragma unroll 1
  for (int s = 0; s < TC_; s++) {
    float u   = b2f((u16)(pk >> 16));
    float dtv = b2f((u16)(pk & 0xffff));
    int sn = (s + 1 < TC_) ? s + 1 : s;
    pk = pp[(size_t)sn * 512];
    dtsum += dtv;
    float du = dtv * u;
    const float* rowp = &sDBC[s * 32];
    #pragma unroll
    for (int g = 0; g < 4; g++) {
      float4 b4 = *(const float4*)&rowp[g * 4];
      int i = g * 4;
      float dA0 = exp2_i(dtv * a2[i + 0]); hl[i + 0] = dA0 * hl[i + 0] + du * b4.x;
      float dA1 = exp2_i(dtv * a2[i + 1]); hl[i + 1] = dA1 * hl[i + 1] + du * b4.y;
      float dA2 = exp2_i(dtv * a2[i + 2]); hl[i + 2] = dA2 * hl[i + 2] + du * b4.z;
      float dA3 = exp2_i(dtv * a2[i + 3]); hl[i + 3] = dA3 * hl[i + 3] + du * b4.w;
    }
  }
  u16 oh[16];
  #pragma unroll
  for (int n = 0; n < 16; n++) oh[n] = f2b(hl[n]);
  size_t o = ((size_t)((b * NC_ + c) * DIN_ + d)) * 16;
  *(uint4*)&chH[o]     = *(const uint4*)&oh[0];
  *(uint4*)&chH[o + 8] = *(const uint4*)&oh[8];
  dts[(size_t)(b * NC_ + c) * DIN_ + d] = dtsum;
}

// mid: sequential combine; ap recomputed from dtsum. 2 states/thread.
__global__ __launch_bounds__(256) void scan_mid_k(
    const u32* __restrict__ chH32, const float* __restrict__ dts,
    const float* __restrict__ a2t, u32* __restrict__ hin32)
{
  int idx = blockIdx.x * 256 + threadIdx.x;   // B*DIN*8 = 32768
  int b = idx >> 12, dk = idx & 4095;
  int d = dk >> 3, k = dk & 7;
  float a20 = a2t[(2 * k) * 512 + d];
  float a21 = a2t[(2 * k + 1) * 512 + d];
  float h0 = 0.f, h1 = 0.f;
  #pragma unroll 4
  for (int c = 0; c < NC_; c++) {
    size_t o = ((size_t)(b * NC_ + c)) * 4096 + dk;
    u32 hh = chH32[o];
    float dsv = dts[(size_t)(b * NC_ + c) * 512 + d];
    hin32[o] = ((u32)f2b(h1) << 16) | (u32)f2b(h0);
    float ap0 = exp2_i(a20 * dsv);
    float ap1 = exp2_i(a21 * dsv);
    h0 = ap0 * h0 + b2f((u16)(hh & 0xffff));
    h1 = ap1 * h1 + b2f((u16)(hh >> 16));
  }
}

// passC: replay from h_in, emit yz
__global__ __launch_bounds__(512) void scan_passC_k(
    const u32* __restrict__ pku,
    const u16* __restrict__ zb,
    const float* __restrict__ xdbc,   // [M,32]: B 0:16, C 16:32
    const float* __restrict__ a2t,
    const u16* __restrict__ hin,      // h_in bf16
    const float* __restrict__ Dv,
    u16* __restrict__ yzb)
{
  __shared__ float sDBC[TC_ * 32];     // 2 KB
  int c = blockIdx.x, b = blockIdx.y, d = threadIdx.x;
  size_t base_row = (size_t)(b * T_ + c * TC_);

  if (d < 128) async16(xdbc + base_row * 32 + d * 4, &sDBC[(d >> 6) * 256]);

  float a2[16], hs[16];
  {
    size_t ho = ((size_t)((b * NC_ + c) * DIN_ + d)) * 16;
    uint4 h0 = *(const uint4*)&hin[ho];
    uint4 h1 = *(const uint4*)&hin[ho + 8];
    const u32* hw = (const u32*)&h0;
    #pragma unroll
    for (int j = 0; j < 4; j++) {
      hs[2 * j]     = b2f((u16)(hw[j] & 0xffff));
      hs[2 * j + 1] = b2f((u16)(hw[j] >> 16));
    }
    const u32* hw1 = (const u32*)&h1;
    #pragma unroll
    for (int j = 0; j < 4; j++) {
      hs[8 + 2 * j]     = b2f((u16)(hw1[j] & 0xffff));
      hs[8 + 2 * j + 1] = b2f((u16)(hw1[j] >> 16));
    }
  }
  #pragma unroll
  for (int n = 0; n < 16; n++) a2[n] = a2t[n * 512 + d];
  float dv = Dv[d];
  const u32* pp = pku + base_row * 512 + d;
  const u16* zp = zb + base_row * 512 + d;
  u32 pk = pp[0];
  u16 zz = zp[0];
  __syncthreads();

  #pragma unroll 1
  for (int s = 0; s < TC_; s++) {
    float u   = b2f((u16)(pk >> 16));
    float dtv = b2f((u16)(pk & 0xffff));
    float z   = b2f(zz);
    int sn = (s + 1 < TC_) ? s + 1 : s;
    pk = pp[(size_t)sn * 512];
    zz = zp[(size_t)sn * 512];
    float du = dtv * u;
    float y = 0.f;
    const float* rowp = &sDBC[s * 32];
    #pragma unroll
    for (int g = 0; g < 4; g++) {
      float4 b4 = *(const float4*)&rowp[g * 4];
      float4 c4 = *(const float4*)&rowp[16 + g * 4];
      int i = g * 4;
      float dA0 = exp2_i(dtv * a2[i + 0]); hs[i + 0] = dA0 * hs[i + 0] + du * b4.x; y += hs[i + 0] * c4.x;
      float dA1 = exp2_i(dtv * a2[i + 1]); hs[i + 1] = dA1 * hs[i + 1] + du * b4.y; y += hs[i + 1] * c4.y;
      float dA2 = exp2_i(dtv * a2[i + 2]); hs[i + 2] = dA2 * hs[i + 2] + du * b4.z; y += hs[i + 2] * c4.z;
      float dA3 = exp2_i(dtv * a2[i + 3]); hs[i + 3] = dA3 * hs[i + 3] + du * b4.w; y += hs[i + 3] * c4.w;
    }
    y += u * dv;
    yzb[(base_row + s) * DIN_ + d] = f2b(y * silu_f(z));
  }
}

// -------------------- pooling + head --------------------
__global__ __launch_bounds__(256) void pool_partial_k(const u16* __restrict__ xn, float* __restrict__ poolP)
{
  int b = blockIdx.x, tc = blockIdx.y, j = threadIdx.x;
  float s = 0.f;
  int t0 = tc * 256;
  #pragma unroll 4
  for (int tt = 0; tt < 256; tt++)
    s += b2f(xn[((size_t)(b * T_ + t0 + tt)) * HID_ + j]);
  poolP[(b * 8 + tc) * HID_ + j] = s;
}

__global__ __launch_bounds__(256) void head_k(
    const float* __restrict__ poolP,
    const float* __restrict__ denW, const float* __restrict__ denb,
    const float* __restrict__ hdW, const float* __restrict__ hdb,
    float* __restrict__ out)
{
  int b = blockIdx.x, j = threadIdx.x;
  float p = 0.f;
  #pragma unroll
  for (int tc = 0; tc < 8; tc++) p += poolP[(b * 8 + tc) * HID_ + j];
  p *= (1.f / 2048.f);
  __shared__ float pl[256], zs[256];
  pl[j] = p;
  __syncthreads();
  float acc = denb[j];
  #pragma unroll 8
  for (int k = 0; k < 256; k++) acc += pl[k] * denW[j * 256 + k];
  zs[j] = fmaxf(acc, 0.f);
  __syncthreads();
  if (j < 2) {
    float o = hdb[j];
    for (int k = 0; k < 256; k++) o += zs[k] * hdW[j * 256 + k];
    out[b * 2 + j] = o;
  }
}

// -------------------- host --------------------
extern "C" void kernel_launch(void* const* d_in, const int* in_sizes, int n_in,
                              void* d_out, int out_size, void* d_ws, size_t ws_size,
                              hipStream_t stream)
{
  const float* tsd   = (const float*)d_in[0];
  const float* stat  = (const float*)d_in[1];
  const float* ta    = (const float*)d_in[2];
  const float* tsW   = (const float*)d_in[3];
  const float* tsb   = (const float*)d_in[4];
  const float* t2vw  = (const float*)d_in[5];
  const float* t2vb  = (const float*)d_in[6];
  const float* timeW = (const float*)d_in[7];
  const float* timeb = (const float*)d_in[8];
  const float* statW = (const float*)d_in[9];
  const float* statb = (const float*)d_in[10];
  const float* lng   = (const float*)d_in[11];
  const float* lnb   = (const float*)d_in[12];
  const float* normw = (const float*)d_in[13];
  const float* ipW   = (const float*)d_in[14];
  const float* convW = (const float*)d_in[15];
  const float* convb = (const float*)d_in[16];
  const float* xpW   = (const float*)d_in[17];
  const float* dpW   = (const float*)d_in[18];
  const float* dpb   = (const float*)d_in[19];
  const float* Alog  = (const float*)d_in[20];
  const float* Dsk   = (const float*)d_in[21];
  const float* opW   = (const float*)d_in[22];
  const float* normf = (const float*)d_in[23];
  const float* denW  = (const float*)d_in[24];
  const float* denb  = (const float*)d_in[25];
  const float* hdW   = (const float*)d_in[26];
  const float* hdb   = (const float*)d_in[27];
  float* out = (float*)d_out;

  float* ws = (float*)d_ws;
  float* h    = ws;  ws += (size_t)B_ * T_ * HID_;          // 16.8 MB
  float* xdbc = ws;  ws += (size_t)B_ * T_ * 32;            // 2.1 MB
  float* poolP= ws;  ws += (size_t)B_ * 8 * HID_;
  float* a2t  = ws;  ws += (size_t)NL_ * NST_ * DIN_;       // 0.13 MB
  float* dts  = ws;  ws += (size_t)B_ * NC_ * DIN_;         // 2.1 MB
  u16* chH    = (u16*)ws;  ws += (size_t)B_ * NC_ * DIN_ * NST_ / 2;  // 16.8 MB
  u16* hin    = (u16*)ws;  ws += (size_t)B_ * NC_ * DIN_ * NST_ / 2;  // 16.8 MB
  u32* pku    = (u32*)ws;  ws += (size_t)B_ * T_ * DIN_;    // 33.5 MB
  u16* xi_b   = (u16*)ws;  ws += (size_t)B_ * T_ * DIN_ / 2;  // 16.8 MB
  u16* z_b    = (u16*)ws;  ws += (size_t)B_ * T_ * DIN_ / 2;  // 16.8 MB
  u16* xn_b   = (u16*)ws;  ws += (size_t)B_ * T_ * HID_ / 2;  // 8.4 MB
  u16* xcb    = (u16*)ws;  ws += (size_t)B_ * T_ * DIN_ / 2;  // 16.8 MB
  u16* yz_b   = (u16*)ws;  ws += (size_t)B_ * T_ * DIN_ / 2;  // 16.8 MB
  u16* wipb   = (u16*)ws;  ws += (size_t)NL_ * 1024 * HID_ / 2;
  u16* wopb   = (u16*)ws;  ws += (size_t)NL_ * HID_ * DIN_ / 2;
  u16* wcomb  = (u16*)ws;  ws += (size_t)NL_ * 640 * DIN_ / 2;  // 2.6 MB

  const int ROWS = B_ * T_;   // 16384

  {
    int nip = NL_ * 1024 * HID_;
    int nop = NL_ * HID_ * DIN_;
    f2b_k<<<nip / 1024, 256, 0, stream>>>(ipW, wipb, nip);
    f2b_k<<<nop / 1024, 256, 0, stream>>>(opW, wopb, nop);
    a2t_k<<<NL_ * NST_ * DIN_ / 256, 256, 0, stream>>>(Alog, a2t);
    wmerge_k<<<dim3(640, NL_), 512, 0, stream>>>(dpW, xpW, wcomb);
  }

  embed_ln_k<<<512, 256, 0, stream>>>(tsd, stat, ta, tsW, tsb, t2vw, t2vb,
                                      timeW, timeb, statW, statb, lng, lnb, h);

  for (int i = 0; i < NL_; i++) {
    const u16* wipbi = wipb + (size_t)i * 1024 * HID_;
    const u16* wopbi = wopb + (size_t)i * HID_ * DIN_;
    const u16* wcombi = wcomb + (size_t)i * 640 * DIN_;
    const float* dpbi = dpb + (size_t)i * DIN_;
    const float* a2ti = a2t + (size_t)i * NST_ * DIN_;

    rmsnorm_k<<<ROWS / 4, 256, 0, stream>>>(h, normw + i * HID_, xn_b);
    // in_proj: one launch, dual dest (xi cols 0:512, z cols 512:1024)
    mgemm_k<4><<<dim3(ROWS / 128, 8), 256, 0, stream>>>(
        xn_b, HID_, wipbi, HID_, xi_b, 512, HID_, nullptr, nullptr, z_b);
    // conv + silu -> xcb bf16
    conv_silu_k<<<ROWS * 64 / 256, 256, 0, stream>>>(xi_b, convW + i * DIN_ * 4, convb + i * DIN_, xcb);
    // dt (merged weight) + B/C in one GEMM: pku + xdbc
    mgemm_k<5><<<dim3(ROWS / 128, 5), 256, 0, stream>>>(
        xcb, DIN_, wcombi, DIN_, pku, 512, DIN_, dpbi, xcb, xdbc);
    // chunked selective scan -> yz bf16
    scan_passA_k<<<dim3(NC_, B_), DIN_, 0, stream>>>(pku, xdbc, a2ti, chH, dts);
    scan_mid_k<<<B_ * DIN_ * 8 / 256, 256, 0, stream>>>((const u32*)chH, dts, a2ti, (u32*)hin);
    scan_passC_k<<<dim3(NC_, B_), DIN_, 0, stream>>>(pku, z_b, xdbc, a2ti, hin,
                                                     Dsk + i * DIN_, yz_b);
    // out_proj + residual -> h f32
    mgemm_k<1><<<dim3(ROWS / 128, HID_ / 128), 256, 0, stream>>>(
        yz_b, DIN_, wopbi, DIN_, h, HID_, DIN_, nullptr, nullptr, nullptr);
  }

  rmsnorm_k<<<ROWS / 4, 256, 0, stream>>>(h, normf, xn_b);
  pool_partial_k<<<dim3(B_, 8), 256, 0, stream>>>(xn_b, poolP);
  head_k<<<B_, 256, 0, stream>>>(poolP, denW, denb, hdW, hdb, out);
}

// Round 12
// 734.995 us; speedup vs baseline: 1.1770x; 1.1770x over previous
//
#include <hip/hip_runtime.h>
#include <math.h>

#define B_ 8
#define T_ 2048
#define HID_ 256
#define DIN_ 512
#define NST_ 16
#define RANK_ 16
#define NL_ 4
#define NC_ 128  // scan chunks
#define TC_ 16   // steps per chunk

typedef unsigned short u16;
typedef unsigned int u32;
typedef __attribute__((ext_vector_type(8))) short bf16x8;
typedef __attribute__((ext_vector_type(4))) float f32x4;

// single-instruction transcendentals (v_exp_f32 = 2^x)
__device__ __forceinline__ float exp2_i(float x) {
  float r; asm("v_exp_f32 %0, %1" : "=v"(r) : "v"(x)); return r;
}
__device__ __forceinline__ float log2_i(float x) {
  float r; asm("v_log_f32 %0, %1" : "=v"(r) : "v"(x)); return r;
}
__device__ __forceinline__ float rcp_i(float x) {
  float r; asm("v_rcp_f32 %0, %1" : "=v"(r) : "v"(x)); return r;
}
#define LOG2E 1.44269504f
#define LN2   0.69314718f

__device__ __forceinline__ float silu_f(float x) {
  return x * rcp_i(1.f + exp2_i(-LOG2E * x));
}
__device__ __forceinline__ float softplus_f(float x) {
  return (x > 20.f) ? x : LN2 * log2_i(1.f + exp2_i(LOG2E * x));
}

__device__ __forceinline__ u16 f2b(float f) {
  union { float f; unsigned u; } v; v.f = f;
  unsigned r = (v.u + 0x7FFFu + ((v.u >> 16) & 1u)) >> 16;
  return (u16)r;
}
__device__ __forceinline__ float b2f(u16 b) {
  union { unsigned u; float f; } v; v.u = ((unsigned)b) << 16;
  return v.f;
}

__device__ __forceinline__ void async16(const void* g, const void* l) {
  __builtin_amdgcn_global_load_lds(
      (const __attribute__((address_space(1))) unsigned int*)g,
      (__attribute__((address_space(3))) unsigned int*)l, 16, 0, 0);
}

// -------------------- f32 -> bf16 convert --------------------
__global__ __launch_bounds__(256) void f2b_k(const float* __restrict__ s, u16* __restrict__ d, int n)
{
  int i = (blockIdx.x * 256 + threadIdx.x) * 4;
  if (i + 3 < n) {
    float4 v = *(const float4*)(s + i);
    d[i + 0] = f2b(v.x); d[i + 1] = f2b(v.y); d[i + 2] = f2b(v.z); d[i + 3] = f2b(v.w);
  } else {
    for (int k = i; k < n; k++) d[k] = f2b(s[k]);
  }
}

// -------------------- a2 transpose prep: a2t[l][n][d] = -exp(Alog[l][d][n])*log2e
__global__ __launch_bounds__(256) void a2t_k(const float* __restrict__ Alog, float* __restrict__ a2t)
{
  int idx = blockIdx.x * 256 + threadIdx.x;   // NL*16*512 = 32768
  int l = idx >> 13, nd = idx & 8191;
  int n = nd >> 9, d = nd & 511;
  float al = Alog[(size_t)l * 8192 + d * 16 + n];
  a2t[(size_t)l * 8192 + n * 512 + d] = -exp2_i(al * LOG2E) * LOG2E;
}

// -------------------- combined dt+BC weight: wcomb[l][640][512] bf16
__global__ __launch_bounds__(512) void wmerge_k(
    const float* __restrict__ dpW,   // [NL,512,16]
    const float* __restrict__ xpW,   // [NL,48,512]
    u16* __restrict__ wcomb)         // [NL,640,512] bf16
{
  int n = blockIdx.x, l = blockIdx.y, k = threadIdx.x;
  const float* xp = xpW + (size_t)l * 48 * 512;
  float acc;
  if (n < 512) {
    const float* dp = dpW + ((size_t)l * 512 + n) * 16;
    acc = 0.f;
    #pragma unroll
    for (int r = 0; r < 16; r++) acc += dp[r] * xp[r * 512 + k];
  } else if (n < 544) {
    acc = xp[(size_t)(16 + n - 512) * 512 + k];
  } else {
    acc = 0.f;
  }
  wcomb[((size_t)l * 640 + n) * 512 + k] = f2b(acc);
}

// -------------------- embed + layernorm (register-weight, 32 rows/block) ------
__global__ __launch_bounds__(256) void embed_ln_k(
    const float* __restrict__ tsd, const float* __restrict__ stat, const float* __restrict__ ta,
    const float* __restrict__ tsW, const float* __restrict__ tsb,
    const float* __restrict__ t2vw, const float* __restrict__ t2vb,
    const float* __restrict__ timeW, const float* __restrict__ timeb,
    const float* __restrict__ statW, const float* __restrict__ statb,
    const float* __restrict__ lng, const float* __restrict__ lnb,
    float* __restrict__ hout)
{
  __shared__ float xts[37 * 32];
  __shared__ float tvs[32 * 32];
  __shared__ float outs[32 * 257];
  __shared__ float smu[32], srs[32];
  int blk = blockIdx.x;             // 512 blocks
  int b = blk >> 6, t0 = (blk & 63) * 32;
  int j = threadIdx.x;

  float wts[37], wtv[32], wst[8];
  #pragma unroll
  for (int m = 0; m < 37; m++) wts[m] = tsW[j * 37 + m];
  #pragma unroll
  for (int e = 0; e < 32; e++) wtv[e] = timeW[j * 32 + e];
  #pragma unroll
  for (int s = 0; s < 8; s++) wst[s] = statW[j * 8 + s];
  float biasj = tsb[j] + timeb[j] + statb[j];
  float lngj = lng[j], lnbj = lnb[j];
  float stq[8];
  #pragma unroll
  for (int s = 0; s < 8; s++) stq[s] = stat[b * 8 + s];

  for (int idx = j; idx < 37 * 32; idx += 256) {
    int m = idx >> 5, tt = idx & 31;
    xts[idx] = tsd[((size_t)b * 37 + m) * T_ + t0 + tt];
  }
  {
    int rr = j >> 5, ee = j & 31;
    #pragma unroll
    for (int rp = 0; rp < 4; rp++) {
      int r = rp * 8 + rr;
      float tav = ta[b * T_ + t0 + r];
      float tv = tav * t2vw[ee] + t2vb[ee];
      tvs[r * 32 + ee] = (ee == 0) ? tv : sinf(tv);
    }
  }
  __syncthreads();

  for (int r = 0; r < 32; r++) {
    float acc = biasj;
    #pragma unroll
    for (int m = 0; m < 37; m++) acc += xts[m * 32 + r] * wts[m];
    #pragma unroll
    for (int e = 0; e < 32; e++) acc += tvs[r * 32 + e] * wtv[e];
    #pragma unroll
    for (int s = 0; s < 8; s++) acc += stq[s] * wst[s];
    outs[r * 257 + j] = acc;
  }
  __syncthreads();
  {
    int r = j >> 3, q = j & 7;
    const float* po = &outs[r * 257 + q * 32];
    float s = 0.f, ss = 0.f;
    #pragma unroll
    for (int i = 0; i < 32; i++) { float v = po[i]; s += v; ss += v * v; }
    s += __shfl_down(s, 1, 64); ss += __shfl_down(ss, 1, 64);
    s += __shfl_down(s, 2, 64); ss += __shfl_down(ss, 2, 64);
    s += __shfl_down(s, 4, 64); ss += __shfl_down(ss, 4, 64);
    if (q == 0) {
      float mu = s * (1.f / 256.f);
      smu[r] = mu;
      srs[r] = rsqrtf(ss * (1.f / 256.f) - mu * mu + 1e-12f);
    }
  }
  __syncthreads();
  for (int r = 0; r < 32; r++) {
    float v = outs[r * 257 + j];
    hout[((size_t)(b * T_ + t0 + r)) * HID_ + j] = (v - smu[r]) * srs[r] * lngj + lnbj;
  }
}

// -------------------- rmsnorm (f32 in -> bf16 out, 1 wave/row) ---------------
__global__ __launch_bounds__(256) void rmsnorm_k(
    const float* __restrict__ x, const float* __restrict__ w, u16* __restrict__ o)
{
  int row = blockIdx.x * 4 + (threadIdx.x >> 6);
  int lane = threadIdx.x & 63;
  float4 v = *(const float4*)&x[(size_t)row * HID_ + lane * 4];
  float ss = v.x * v.x + v.y * v.y + v.z * v.z + v.w * v.w;
  #pragma unroll
  for (int ofs = 32; ofs > 0; ofs >>= 1) ss += __shfl_xor(ss, ofs, 64);
  float sc = rsqrtf(ss * (1.f / 256.f) + 1e-5f);
  float4 wv = *(const float4*)&w[lane * 4];
  u16 r[4];
  r[0] = f2b(v.x * sc * wv.x); r[1] = f2b(v.y * sc * wv.y);
  r[2] = f2b(v.z * sc * wv.z); r[3] = f2b(v.w * sc * wv.w);
  *(uint2*)&o[(size_t)row * HID_ + lane * 4] = *(const uint2*)r;
}

// -------------------- bf16 MFMA GEMM: C[M,N] = A @ W^T ----------------------
// MODE 1: f32 out + residual (out_proj)
// MODE 4: bf16 out via LDS epilogue, dual dest split at col 512 (in_proj)
// MODE 6: cols<512: softplus(acc+bias) -> bf16 dtb (LDS epilogue);
//         cols 512:544: f32 direct -> Cv2 [M,32]
template <int MODE>
__global__ __launch_bounds__(256) void mgemm_k(
    const u16* __restrict__ A, int lda,
    const u16* __restrict__ W, int ldw,
    void* __restrict__ Cv, int ldc,
    int K,
    const float* __restrict__ bias,
    void* __restrict__ Cv2)
{
  __shared__ u16 smem[128 * 136];   // 34816 B: tiles (2x8192) + epilogue stage
  u16* sA = smem;
  u16* sB = smem + 128 * 64;
  const int tid = threadIdx.x;
  const int bm = blockIdx.x * 128, bn = blockIdx.y * 128;
  const int w = tid >> 6, l = tid & 63;
  const int wm = (w & 1) * 64, wn = (w >> 1) * 64;
  const int lr = l & 15, lh = l >> 4;

  f32x4 acc[4][4] = {};

  const int srow = tid >> 3;
  const int schunk = tid & 7;

  for (int k0 = 0; k0 < K; k0 += 64) {
    #pragma unroll
    for (int c = 0; c < 4; c++) {
      int row = c * 32 + srow;
      int g = schunk ^ (row & 7);
      async16(A + (size_t)(bm + row) * lda + k0 + g * 8, &sA[c * 2048 + w * 512]);
      async16(W + (size_t)(bn + row) * ldw + k0 + g * 8, &sB[c * 2048 + w * 512]);
    }
    __syncthreads();
    #pragma unroll
    for (int kk = 0; kk < 2; kk++) {
      bf16x8 af[4], bfr[4];
      #pragma unroll
      for (int i = 0; i < 4; i++) {
        int ra = wm + i * 16 + lr;
        int rb = wn + i * 16 + lr;
        int e = kk * 4 + lh;
        af[i]  = *(const bf16x8*)&sA[ra * 64 + ((e ^ (ra & 7)) * 8)];
        bfr[i] = *(const bf16x8*)&sB[rb * 64 + ((e ^ (rb & 7)) * 8)];
      }
      #pragma unroll
      for (int i = 0; i < 4; i++)
        #pragma unroll
        for (int j = 0; j < 4; j++)
          acc[i][j] = __builtin_amdgcn_mfma_f32_16x16x32_bf16(af[i], bfr[j], acc[i][j], 0, 0, 0);
    }
    __syncthreads();
  }

  if (MODE == 1) {
    #pragma unroll
    for (int i = 0; i < 4; i++) {
      int m = bm + wm + i * 16 + lh * 4;
      #pragma unroll
      for (int j = 0; j < 4; j++) {
        int n = bn + wn + j * 16 + lr;
        float* cp = (float*)Cv + (size_t)m * ldc + n;
        #pragma unroll
        for (int r = 0; r < 4; r++)
          cp[(size_t)r * ldc] = acc[i][j][r] + cp[(size_t)r * ldc];
      }
    }
  } else if (MODE == 6 && bn >= 512) {
    // BC part: f32 direct, keep cols 512..543
    #pragma unroll
    for (int i = 0; i < 4; i++) {
      int m = bm + wm + i * 16 + lh * 4;
      #pragma unroll
      for (int j = 0; j < 4; j++) {
        int n = bn + wn + j * 16 + lr;
        if (n < 544) {
          #pragma unroll
          for (int r = 0; r < 4; r++)
            ((float*)Cv2)[(size_t)(m + r) * 32 + (n - 512)] = acc[i][j][r];
        }
      }
    }
  } else {
    // bf16 LDS-staged coalesced epilogue (MODE 4, MODE 6 dt-part)
    u16* eps = smem;                 // 128 x 136 u16
    float bv[4];
    if (MODE == 6) {
      #pragma unroll
      for (int j = 0; j < 4; j++) bv[j] = bias[bn + wn + j * 16 + lr];
    }
    #pragma unroll
    for (int i = 0; i < 4; i++) {
      int rr = wm + i * 16 + lh * 4;
      #pragma unroll
      for (int j = 0; j < 4; j++) {
        int cc = wn + j * 16 + lr;
        #pragma unroll
        for (int r = 0; r < 4; r++) {
          float v = acc[i][j][r];
          if (MODE == 6) v = softplus_f(v + bv[j]);
          eps[(rr + r) * 136 + cc] = f2b(v);
        }
      }
    }
    __syncthreads();
    u16* dbase; int c0;
    if (MODE == 4 && bn >= 512) { dbase = (u16*)Cv2; c0 = bn - 512; }
    else                        { dbase = (u16*)Cv;  c0 = bn; }
    #pragma unroll
    for (int q = 0; q < 8; q++) {
      int flat = q * 256 + tid;          // 0..2047
      int row = flat >> 4, cv = flat & 15;
      *(uint4*)&dbase[(size_t)(bm + row) * 512 + c0 + cv * 8] =
          *(const uint4*)&eps[row * 136 + cv * 8];
    }
  }
}

// -------------------- causal depthwise conv + silu (bf16 in/out, 8 d/thread) --
__global__ __launch_bounds__(256) void conv_silu_k(
    const u16* __restrict__ xib,      // [B*T,512] bf16
    const float* __restrict__ cw,     // [512,4]
    const float* __restrict__ cb,     // [512]
    u16* __restrict__ xcb)            // [B*T,512] bf16
{
  int idx = blockIdx.x * 256 + threadIdx.x;   // ROWS*64 threads
  int row = idx >> 6;
  int t = row & (T_ - 1);
  int d0 = (idx & 63) << 3;

  float acc[8];
  *(float4*)&acc[0] = *(const float4*)&cb[d0];
  *(float4*)&acc[4] = *(const float4*)&cb[d0 + 4];
  float wreg[8][4];
  #pragma unroll
  for (int j = 0; j < 8; j++)
    *(float4*)&wreg[j][0] = *(const float4*)&cw[(d0 + j) * 4];

  #pragma unroll
  for (int k = 0; k < 4; k++) {
    int tt = t + k - 3;
    if (tt >= 0) {
      bf16x8 v = *(const bf16x8*)&xib[(size_t)(row + k - 3) * 512 + d0];
      #pragma unroll
      for (int j = 0; j < 8; j++) acc[j] += wreg[j][k] * b2f((u16)v[j]);
    }
  }
  u16 o[8];
  #pragma unroll
  for (int j = 0; j < 8; j++) o[j] = f2b(silu_f(acc[j]));
  *(bf16x8*)&xcb[(size_t)row * 512 + d0] = *(const bf16x8*)o;
}

// -------------------- chunked selective scan --------------------
// passA: local scan with h_in=0; store hl (bf16) + dtsum (f32)
__global__ __launch_bounds__(512) void scan_passA_k(
    const u16* __restrict__ xcb,      // u bf16 [B*T,512]
    const u16* __restrict__ dtb,      // dt bf16 [B*T,512]
    const float* __restrict__ xdbc,   // [M,32]: B cols 0:16
    const float* __restrict__ a2t,    // [16][512]
    u16* __restrict__ chH, float* __restrict__ dts)
{
  __shared__ float sDBC[TC_ * 32];     // 2 KB
  int c = blockIdx.x, b = blockIdx.y, d = threadIdx.x;
  size_t base_row = (size_t)(b * T_ + c * TC_);

  if (d < 128) async16(xdbc + base_row * 32 + d * 4, &sDBC[(d >> 6) * 256]);

  float a2[16], hl[16];
  #pragma unroll
  for (int n = 0; n < 16; n++) { a2[n] = a2t[n * 512 + d]; hl[n] = 0.f; }
  float dtsum = 0.f;
  const u16* up = xcb + base_row * 512 + d;
  const u16* tp = dtb + base_row * 512 + d;
  u16 pu = up[0], pt = tp[0];
  __syncthreads();

  #pragma unroll 1
  for (int s = 0; s < TC_; s++) {
    float u   = b2f(pu);
    float dtv = b2f(pt);
    int sn = (s + 1 < TC_) ? s + 1 : s;
    pu = up[(size_t)sn * 512];
    pt = tp[(size_t)sn * 512];
    dtsum += dtv;
    float du = dtv * u;
    const float* rowp = &sDBC[s * 32];
    #pragma unroll
    for (int g = 0; g < 4; g++) {
      float4 b4 = *(const float4*)&rowp[g * 4];
      int i = g * 4;
      float dA0 = exp2_i(dtv * a2[i + 0]); hl[i + 0] = dA0 * hl[i + 0] + du * b4.x;
      float dA1 = exp2_i(dtv * a2[i + 1]); hl[i + 1] = dA1 * hl[i + 1] + du * b4.y;
      float dA2 = exp2_i(dtv * a2[i + 2]); hl[i + 2] = dA2 * hl[i + 2] + du * b4.z;
      float dA3 = exp2_i(dtv * a2[i + 3]); hl[i + 3] = dA3 * hl[i + 3] + du * b4.w;
    }
  }
  u16 oh[16];
  #pragma unroll
  for (int n = 0; n < 16; n++) oh[n] = f2b(hl[n]);
  size_t o = ((size_t)((b * NC_ + c) * DIN_ + d)) * 16;
  *(uint4*)&chH[o]     = *(const uint4*)&oh[0];
  *(uint4*)&chH[o + 8] = *(const uint4*)&oh[8];
  dts[(size_t)(b * NC_ + c) * DIN_ + d] = dtsum;
}

// mid: sequential combine; ap recomputed from dtsum. 2 states/thread.
__global__ __launch_bounds__(256) void scan_mid_k(
    const u32* __restrict__ chH32, const float* __restrict__ dts,
    const float* __restrict__ a2t, u32* __restrict__ hin32)
{
  int idx = blockIdx.x * 256 + threadIdx.x;   // B*DIN*8 = 32768
  int b = idx >> 12, dk = idx & 4095;
  int d = dk >> 3, k = dk & 7;
  float a20 = a2t[(2 * k) * 512 + d];
  float a21 = a2t[(2 * k + 1) * 512 + d];
  float h0 = 0.f, h1 = 0.f;
  #pragma unroll 8
  for (int c = 0; c < NC_; c++) {
    size_t o = ((size_t)(b * NC_ + c)) * 4096 + dk;
    u32 hh = chH32[o];
    float dsv = dts[(size_t)(b * NC_ + c) * 512 + d];
    hin32[o] = ((u32)f2b(h1) << 16) | (u32)f2b(h0);
    float ap0 = exp2_i(a20 * dsv);
    float ap1 = exp2_i(a21 * dsv);
    h0 = ap0 * h0 + b2f((u16)(hh & 0xffff));
    h1 = ap1 * h1 + b2f((u16)(hh >> 16));
  }
}

// passC: replay from h_in, emit yz
__global__ __launch_bounds__(512) void scan_passC_k(
    const u16* __restrict__ xcb,
    const u16* __restrict__ dtb,
    const u16* __restrict__ zb,
    const float* __restrict__ xdbc,   // [M,32]: B 0:16, C 16:32
    const float* __restrict__ a2t,
    const u16* __restrict__ hin,      // h_in bf16
    const float* __restrict__ Dv,
    u16* __restrict__ yzb)
{
  __shared__ float sDBC[TC_ * 32];     // 2 KB
  int c = blockIdx.x, b = blockIdx.y, d = threadIdx.x;
  size_t base_row = (size_t)(b * T_ + c * TC_);

  if (d < 128) async16(xdbc + base_row * 32 + d * 4, &sDBC[(d >> 6) * 256]);

  float a2[16], hs[16];
  {
    size_t ho = ((size_t)((b * NC_ + c) * DIN_ + d)) * 16;
    uint4 h0 = *(const uint4*)&hin[ho];
    uint4 h1 = *(const uint4*)&hin[ho + 8];
    const u32* hw = (const u32*)&h0;
    #pragma unroll
    for (int j = 0; j < 4; j++) {
      hs[2 * j]     = b2f((u16)(hw[j] & 0xffff));
      hs[2 * j + 1] = b2f((u16)(hw[j] >> 16));
    }
    const u32* hw1 = (const u32*)&h1;
    #pragma unroll
    for (int j = 0; j < 4; j++) {
      hs[8 + 2 * j]     = b2f((u16)(hw1[j] & 0xffff));
      hs[8 + 2 * j + 1] = b2f((u16)(hw1[j] >> 16));
    }
  }
  #pragma unroll
  for (int n = 0; n < 16; n++) a2[n] = a2t[n * 512 + d];
  float dv = Dv[d];
  const u16* up = xcb + base_row * 512 + d;
  const u16* tp = dtb + base_row * 512 + d;
  const u16* zp = zb + base_row * 512 + d;
  u16 pu = up[0], pt = tp[0], zz = zp[0];
  __syncthreads();

  #pragma unroll 1
  for (int s = 0; s < TC_; s++) {
    float u   = b2f(pu);
    float dtv = b2f(pt);
    float z   = b2f(zz);
    int sn = (s + 1 < TC_) ? s + 1 : s;
    pu = up[(size_t)sn * 512];
    pt = tp[(size_t)sn * 512];
    zz = zp[(size_t)sn * 512];
    float du = dtv * u;
    float y = 0.f;
    const float* rowp = &sDBC[s * 32];
    #pragma unroll
    for (int g = 0; g < 4; g++) {
      float4 b4 = *(const float4*)&rowp[g * 4];
      float4 c4 = *(const float4*)&rowp[16 + g * 4];
      int i = g * 4;
      float dA0 = exp2_i(dtv * a2[i + 0]); hs[i + 0] = dA0 * hs[i + 0] + du * b4.x; y += hs[i + 0] * c4.x;
      float dA1 = exp2_i(dtv * a2[i + 1]); hs[i + 1] = dA1 * hs[i + 1] + du * b4.y; y += hs[i + 1] * c4.y;
      float dA2 = exp2_i(dtv * a2[i + 2]); hs[i + 2] = dA2 * hs[i + 2] + du * b4.z; y += hs[i + 2] * c4.z;
      float dA3 = exp2_i(dtv * a2[i + 3]); hs[i + 3] = dA3 * hs[i + 3] + du * b4.w; y += hs[i + 3] * c4.w;
    }
    y += u * dv;
    yzb[(base_row + s) * DIN_ + d] = f2b(y * silu_f(z));
  }
}

// -------------------- pooling + head --------------------
__global__ __launch_bounds__(256) void pool_partial_k(const u16* __restrict__ xn, float* __restrict__ poolP)
{
  int b = blockIdx.x, tc = blockIdx.y, j = threadIdx.x;
  float s = 0.f;
  int t0 = tc * 256;
  #pragma unroll 4
  for (int tt = 0; tt < 256; tt++)
    s += b2f(xn[((size_t)(b * T_ + t0 + tt)) * HID_ + j]);
  poolP[(b * 8 + tc) * HID_ + j] = s;
}

__global__ __launch_bounds__(256) void head_k(
    const float* __restrict__ poolP,
    const float* __restrict__ denW, const float* __restrict__ denb,
    const float* __restrict__ hdW, const float* __restrict__ hdb,
    float* __restrict__ out)
{
  int b = blockIdx.x, j = threadIdx.x;
  float p = 0.f;
  #pragma unroll
  for (int tc = 0; tc < 8; tc++) p += poolP[(b * 8 + tc) * HID_ + j];
  p *= (1.f / 2048.f);
  __shared__ float pl[256], zs[256];
  pl[j] = p;
  __syncthreads();
  float acc = denb[j];
  #pragma unroll 8
  for (int k = 0; k < 256; k++) acc += pl[k] * denW[j * 256 + k];
  zs[j] = fmaxf(acc, 0.f);
  __syncthreads();
  if (j < 2) {
    float o = hdb[j];
    for (int k = 0; k < 256; k++) o += zs[k] * hdW[j * 256 + k];
    out[b * 2 + j] = o;
  }
}

// -------------------- host --------------------
extern "C" void kernel_launch(void* const* d_in, const int* in_sizes, int n_in,
                              void* d_out, int out_size, void* d_ws, size_t ws_size,
                              hipStream_t stream)
{
  const float* tsd   = (const float*)d_in[0];
  const float* stat  = (const float*)d_in[1];
  const float* ta    = (const float*)d_in[2];
  const float* tsW   = (const float*)d_in[3];
  const float* tsb   = (const float*)d_in[4];
  const float* t2vw  = (const float*)d_in[5];
  const float* t2vb  = (const float*)d_in[6];
  const float* timeW = (const float*)d_in[7];
  const float* timeb = (const float*)d_in[8];
  const float* statW = (const float*)d_in[9];
  const float* statb = (const float*)d_in[10];
  const float* lng   = (const float*)d_in[11];
  const float* lnb   = (const float*)d_in[12];
  const float* normw = (const float*)d_in[13];
  const float* ipW   = (const float*)d_in[14];
  const float* convW = (const float*)d_in[15];
  const float* convb = (const float*)d_in[16];
  const float* xpW   = (const float*)d_in[17];
  const float* dpW   = (const float*)d_in[18];
  const float* dpb   = (const float*)d_in[19];
  const float* Alog  = (const float*)d_in[20];
  const float* Dsk   = (const float*)d_in[21];
  const float* opW   = (const float*)d_in[22];
  const float* normf = (const float*)d_in[23];
  const float* denW  = (const float*)d_in[24];
  const float* denb  = (const float*)d_in[25];
  const float* hdW   = (const float*)d_in[26];
  const float* hdb   = (const float*)d_in[27];
  float* out = (float*)d_out;

  float* ws = (float*)d_ws;
  float* h    = ws;  ws += (size_t)B_ * T_ * HID_;          // 16.8 MB
  float* xdbc = ws;  ws += (size_t)B_ * T_ * 32;            // 2.1 MB
  float* poolP= ws;  ws += (size_t)B_ * 8 * HID_;
  float* a2t  = ws;  ws += (size_t)NL_ * NST_ * DIN_;       // 0.13 MB
  float* dts  = ws;  ws += (size_t)B_ * NC_ * DIN_;         // 2.1 MB
  u16* chH    = (u16*)ws;  ws += (size_t)B_ * NC_ * DIN_ * NST_ / 2;  // 16.8 MB
  u16* hin    = (u16*)ws;  ws += (size_t)B_ * NC_ * DIN_ * NST_ / 2;  // 16.8 MB
  u16* dtb    = (u16*)ws;  ws += (size_t)B_ * T_ * DIN_ / 2;  // 16.8 MB
  u16* xi_b   = (u16*)ws;  ws += (size_t)B_ * T_ * DIN_ / 2;  // 16.8 MB
  u16* z_b    = (u16*)ws;  ws += (size_t)B_ * T_ * DIN_ / 2;  // 16.8 MB
  u16* xn_b   = (u16*)ws;  ws += (size_t)B_ * T_ * HID_ / 2;  // 8.4 MB
  u16* xcb    = (u16*)ws;  ws += (size_t)B_ * T_ * DIN_ / 2;  // 16.8 MB
  u16* yz_b   = (u16*)ws;  ws += (size_t)B_ * T_ * DIN_ / 2;  // 16.8 MB
  u16* wipb   = (u16*)ws;  ws += (size_t)NL_ * 1024 * HID_ / 2;
  u16* wopb   = (u16*)ws;  ws += (size_t)NL_ * HID_ * DIN_ / 2;
  u16* wcomb  = (u16*)ws;  ws += (size_t)NL_ * 640 * DIN_ / 2;  // 2.6 MB

  const int ROWS = B_ * T_;   // 16384

  {
    int nip = NL_ * 1024 * HID_;
    int nop = NL_ * HID_ * DIN_;
    f2b_k<<<nip / 1024, 256, 0, stream>>>(ipW, wipb, nip);
    f2b_k<<<nop / 1024, 256, 0, stream>>>(opW, wopb, nop);
    a2t_k<<<NL_ * NST_ * DIN_ / 256, 256, 0, stream>>>(Alog, a2t);
    wmerge_k<<<dim3(640, NL_), 512, 0, stream>>>(dpW, xpW, wcomb);
  }

  embed_ln_k<<<512, 256, 0, stream>>>(tsd, stat, ta, tsW, tsb, t2vw, t2vb,
                                      timeW, timeb, statW, statb, lng, lnb, h);

  for (int i = 0; i < NL_; i++) {
    const u16* wipbi = wipb + (size_t)i * 1024 * HID_;
    const u16* wopbi = wopb + (size_t)i * HID_ * DIN_;
    const u16* wcombi = wcomb + (size_t)i * 640 * DIN_;
    const float* dpbi = dpb + (size_t)i * DIN_;
    const float* a2ti = a2t + (size_t)i * NST_ * DIN_;

    rmsnorm_k<<<ROWS / 4, 256, 0, stream>>>(h, normw + i * HID_, xn_b);
    // in_proj: one launch, dual dest (xi cols 0:512, z cols 512:1024)
    mgemm_k<4><<<dim3(ROWS / 128, 8), 256, 0, stream>>>(
        xn_b, HID_, wipbi, HID_, xi_b, 512, HID_, nullptr, z_b);
    // conv + silu -> xcb bf16
    conv_silu_k<<<ROWS * 64 / 256, 256, 0, stream>>>(xi_b, convW + i * DIN_ * 4, convb + i * DIN_, xcb);
    // dt (merged weight, softplus fused) -> dtb; B/C -> xdbc
    mgemm_k<6><<<dim3(ROWS / 128, 5), 256, 0, stream>>>(
        xcb, DIN_, wcombi, DIN_, dtb, 512, DIN_, dpbi, xdbc);
    // chunked selective scan -> yz bf16
    scan_passA_k<<<dim3(NC_, B_), DIN_, 0, stream>>>(xcb, dtb, xdbc, a2ti, chH, dts);
    scan_mid_k<<<B_ * DIN_ * 8 / 256, 256, 0, stream>>>((const u32*)chH, dts, a2ti, (u32*)hin);
    scan_passC_k<<<dim3(NC_, B_), DIN_, 0, stream>>>(xcb, dtb, z_b, xdbc, a2ti, hin,
                                                     Dsk + i * DIN_, yz_b);
    // out_proj + residual -> h f32
    mgemm_k<1><<<dim3(ROWS / 128, HID_ / 128), 256, 0, stream>>>(
        yz_b, DIN_, wopbi, DIN_, h, HID_, DIN_, nullptr, nullptr);
  }

  rmsnorm_k<<<ROWS / 4, 256, 0, stream>>>(h, normf, xn_b);
  pool_partial_k<<<dim3(B_, 8), 256, 0, stream>>>(xn_b, poolP);
  head_k<<<B_, 256, 0, stream>>>(poolP, denW, denb, hdW, hdb, out);
}

// Round 13
// 700.383 us; speedup vs baseline: 1.2351x; 1.0494x over previous
//
#include <hip/hip_runtime.h>
#include <math.h>

#define B_ 8
#define T_ 2048
#define HID_ 256
#define DIN_ 512
#define NST_ 16
#define RANK_ 16
#define NL_ 4
#define NC_ 128  // scan chunks
#define TC_ 16   // steps per chunk

typedef unsigned short u16;
typedef unsigned int u32;
typedef __attribute__((ext_vector_type(8))) short bf16x8;
typedef __attribute__((ext_vector_type(4))) float f32x4;

__device__ __forceinline__ float exp2_i(float x) {
  float r; asm("v_exp_f32 %0, %1" : "=v"(r) : "v"(x)); return r;
}
__device__ __forceinline__ float log2_i(float x) {
  float r; asm("v_log_f32 %0, %1" : "=v"(r) : "v"(x)); return r;
}
__device__ __forceinline__ float rcp_i(float x) {
  float r; asm("v_rcp_f32 %0, %1" : "=v"(r) : "v"(x)); return r;
}
#define LOG2E 1.44269504f
#define LN2   0.69314718f

__device__ __forceinline__ float silu_f(float x) {
  return x * rcp_i(1.f + exp2_i(-LOG2E * x));
}
__device__ __forceinline__ float softplus_f(float x) {
  return (x > 20.f) ? x : LN2 * log2_i(1.f + exp2_i(LOG2E * x));
}

__device__ __forceinline__ u16 f2b(float f) {
  union { float f; unsigned u; } v; v.f = f;
  unsigned r = (v.u + 0x7FFFu + ((v.u >> 16) & 1u)) >> 16;
  return (u16)r;
}
__device__ __forceinline__ float b2f(u16 b) {
  union { unsigned u; float f; } v; v.u = ((unsigned)b) << 16;
  return v.f;
}

__device__ __forceinline__ void async16(const void* g, const void* l) {
  __builtin_amdgcn_global_load_lds(
      (const __attribute__((address_space(1))) unsigned int*)g,
      (__attribute__((address_space(3))) unsigned int*)l, 16, 0, 0);
}

// -------------------- f32 -> bf16 convert --------------------
__global__ __launch_bounds__(256) void f2b_k(const float* __restrict__ s, u16* __restrict__ d, int n)
{
  int i = (blockIdx.x * 256 + threadIdx.x) * 4;
  if (i + 3 < n) {
    float4 v = *(const float4*)(s + i);
    d[i + 0] = f2b(v.x); d[i + 1] = f2b(v.y); d[i + 2] = f2b(v.z); d[i + 3] = f2b(v.w);
  } else {
    for (int k = i; k < n; k++) d[k] = f2b(s[k]);
  }
}

// -------------------- a2 transpose prep --------------------
__global__ __launch_bounds__(256) void a2t_k(const float* __restrict__ Alog, float* __restrict__ a2t)
{
  int idx = blockIdx.x * 256 + threadIdx.x;   // NL*16*512 = 32768
  int l = idx >> 13, nd = idx & 8191;
  int n = nd >> 9, d = nd & 511;
  float al = Alog[(size_t)l * 8192 + d * 16 + n];
  a2t[(size_t)l * 8192 + n * 512 + d] = -exp2_i(al * LOG2E) * LOG2E;
}

// -------------------- combined dt+BC weight: wcomb[l][640][512] bf16
__global__ __launch_bounds__(512) void wmerge_k(
    const float* __restrict__ dpW,   // [NL,512,16]
    const float* __restrict__ xpW,   // [NL,48,512]
    u16* __restrict__ wcomb)         // [NL,640,512] bf16
{
  int n = blockIdx.x, l = blockIdx.y, k = threadIdx.x;
  const float* xp = xpW + (size_t)l * 48 * 512;
  float acc;
  if (n < 512) {
    const float* dp = dpW + ((size_t)l * 512 + n) * 16;
    acc = 0.f;
    #pragma unroll
    for (int r = 0; r < 16; r++) acc += dp[r] * xp[r * 512 + k];
  } else if (n < 544) {
    acc = xp[(size_t)(16 + n - 512) * 512 + k];
  } else {
    acc = 0.f;
  }
  wcomb[((size_t)l * 640 + n) * 512 + k] = f2b(acc);
}

// -------------------- embed + layernorm + rmsnorm(normw0) ------------------
__global__ __launch_bounds__(256) void embed_ln_k(
    const float* __restrict__ tsd, const float* __restrict__ stat, const float* __restrict__ ta,
    const float* __restrict__ tsW, const float* __restrict__ tsb,
    const float* __restrict__ t2vw, const float* __restrict__ t2vb,
    const float* __restrict__ timeW, const float* __restrict__ timeb,
    const float* __restrict__ statW, const float* __restrict__ statb,
    const float* __restrict__ lng, const float* __restrict__ lnb,
    const float* __restrict__ nw0,
    float* __restrict__ hout, u16* __restrict__ xnb)
{
  __shared__ float xts[37 * 32];
  __shared__ float tvs[32 * 32];
  __shared__ float outs[32 * 257];
  __shared__ float smu[32], srs[32], srs2[32];
  int blk = blockIdx.x;             // 512 blocks
  int b = blk >> 6, t0 = (blk & 63) * 32;
  int j = threadIdx.x;

  float wts[37], wtv[32], wst[8];
  #pragma unroll
  for (int m = 0; m < 37; m++) wts[m] = tsW[j * 37 + m];
  #pragma unroll
  for (int e = 0; e < 32; e++) wtv[e] = timeW[j * 32 + e];
  #pragma unroll
  for (int s = 0; s < 8; s++) wst[s] = statW[j * 8 + s];
  float biasj = tsb[j] + timeb[j] + statb[j];
  float lngj = lng[j], lnbj = lnb[j];
  float nw0j = nw0[j];
  float stq[8];
  #pragma unroll
  for (int s = 0; s < 8; s++) stq[s] = stat[b * 8 + s];

  for (int idx = j; idx < 37 * 32; idx += 256) {
    int m = idx >> 5, tt = idx & 31;
    xts[idx] = tsd[((size_t)b * 37 + m) * T_ + t0 + tt];
  }
  {
    int rr = j >> 5, ee = j & 31;
    #pragma unroll
    for (int rp = 0; rp < 4; rp++) {
      int r = rp * 8 + rr;
      float tav = ta[b * T_ + t0 + r];
      float tv = tav * t2vw[ee] + t2vb[ee];
      tvs[r * 32 + ee] = (ee == 0) ? tv : sinf(tv);
    }
  }
  __syncthreads();

  for (int r = 0; r < 32; r++) {
    float acc = biasj;
    #pragma unroll
    for (int m = 0; m < 37; m++) acc += xts[m * 32 + r] * wts[m];
    #pragma unroll
    for (int e = 0; e < 32; e++) acc += tvs[r * 32 + e] * wtv[e];
    #pragma unroll
    for (int s = 0; s < 8; s++) acc += stq[s] * wst[s];
    outs[r * 257 + j] = acc;
  }
  __syncthreads();
  {
    int r = j >> 3, q = j & 7;
    const float* po = &outs[r * 257 + q * 32];
    float s = 0.f, ss = 0.f;
    #pragma unroll
    for (int i = 0; i < 32; i++) { float v = po[i]; s += v; ss += v * v; }
    s += __shfl_down(s, 1, 64); ss += __shfl_down(ss, 1, 64);
    s += __shfl_down(s, 2, 64); ss += __shfl_down(ss, 2, 64);
    s += __shfl_down(s, 4, 64); ss += __shfl_down(ss, 4, 64);
    if (q == 0) {
      float mu = s * (1.f / 256.f);
      smu[r] = mu;
      srs[r] = rsqrtf(ss * (1.f / 256.f) - mu * mu + 1e-12f);
    }
  }
  __syncthreads();
  for (int r = 0; r < 32; r++) {
    float v = outs[r * 257 + j];
    float hv = (v - smu[r]) * srs[r] * lngj + lnbj;
    hout[((size_t)(b * T_ + t0 + r)) * HID_ + j] = hv;
    outs[r * 257 + j] = hv;
  }
  __syncthreads();
  {
    int r = j >> 3, q = j & 7;
    const float* po = &outs[r * 257 + q * 32];
    float ss = 0.f;
    #pragma unroll
    for (int i = 0; i < 32; i++) { float v = po[i]; ss += v * v; }
    ss += __shfl_down(ss, 1, 64);
    ss += __shfl_down(ss, 2, 64);
    ss += __shfl_down(ss, 4, 64);
    if (q == 0) srs2[r] = rsqrtf(ss * (1.f / 256.f) + 1e-5f);
  }
  __syncthreads();
  for (int r = 0; r < 32; r++) {
    xnb[((size_t)(b * T_ + t0 + r)) * HID_ + j] = f2b(outs[r * 257 + j] * srs2[r] * nw0j);
  }
}

// -------------------- bf16 MFMA GEMM 128x128: C[M,N] = A @ W^T --------------
// MODE 4: bf16 out via LDS epilogue, dual dest split at col 512 (in_proj)
// MODE 6: cols<512: softplus(acc+bias) -> bf16 dtb; cols 512:544: f32 -> Cv2
template <int MODE>
__global__ __launch_bounds__(256) void mgemm_k(
    const u16* __restrict__ A, int lda,
    const u16* __restrict__ W, int ldw,
    void* __restrict__ Cv, int ldc,
    int K,
    const float* __restrict__ bias,
    void* __restrict__ Cv2)
{
  __shared__ u16 smem[128 * 136];   // tiles (2x8192) / epilogue stage
  u16* sA = smem;
  u16* sB = smem + 128 * 64;
  const int tid = threadIdx.x;
  const int bm = blockIdx.x * 128, bn = blockIdx.y * 128;
  const int w = tid >> 6, l = tid & 63;
  const int wm = (w & 1) * 64, wn = (w >> 1) * 64;
  const int lr = l & 15, lh = l >> 4;

  f32x4 acc[4][4] = {};

  const int srow = tid >> 3;
  const int schunk = tid & 7;

  for (int k0 = 0; k0 < K; k0 += 64) {
    #pragma unroll
    for (int c = 0; c < 4; c++) {
      int row = c * 32 + srow;
      int g = schunk ^ (row & 7);
      async16(A + (size_t)(bm + row) * lda + k0 + g * 8, &sA[c * 2048 + w * 512]);
      async16(W + (size_t)(bn + row) * ldw + k0 + g * 8, &sB[c * 2048 + w * 512]);
    }
    __syncthreads();
    #pragma unroll
    for (int kk = 0; kk < 2; kk++) {
      bf16x8 af[4], bfr[4];
      #pragma unroll
      for (int i = 0; i < 4; i++) {
        int ra = wm + i * 16 + lr;
        int rb = wn + i * 16 + lr;
        int e = kk * 4 + lh;
        af[i]  = *(const bf16x8*)&sA[ra * 64 + ((e ^ (ra & 7)) * 8)];
        bfr[i] = *(const bf16x8*)&sB[rb * 64 + ((e ^ (rb & 7)) * 8)];
      }
      #pragma unroll
      for (int i = 0; i < 4; i++)
        #pragma unroll
        for (int j = 0; j < 4; j++)
          acc[i][j] = __builtin_amdgcn_mfma_f32_16x16x32_bf16(af[i], bfr[j], acc[i][j], 0, 0, 0);
    }
    __syncthreads();
  }

  if (MODE == 6 && bn >= 512) {
    #pragma unroll
    for (int i = 0; i < 4; i++) {
      int m = bm + wm + i * 16 + lh * 4;
      #pragma unroll
      for (int j = 0; j < 4; j++) {
        int n = bn + wn + j * 16 + lr;
        if (n < 544) {
          #pragma unroll
          for (int r = 0; r < 4; r++)
            ((float*)Cv2)[(size_t)(m + r) * 32 + (n - 512)] = acc[i][j][r];
        }
      }
    }
  } else {
    u16* eps = smem;                 // 128 x 136 u16
    float bv[4];
    if (MODE == 6) {
      #pragma unroll
      for (int j = 0; j < 4; j++) bv[j] = bias[bn + wn + j * 16 + lr];
    }
    #pragma unroll
    for (int i = 0; i < 4; i++) {
      int rr = wm + i * 16 + lh * 4;
      #pragma unroll
      for (int j = 0; j < 4; j++) {
        int cc = wn + j * 16 + lr;
        #pragma unroll
        for (int r = 0; r < 4; r++) {
          float v = acc[i][j][r];
          if (MODE == 6) v = softplus_f(v + bv[j]);
          eps[(rr + r) * 136 + cc] = f2b(v);
        }
      }
    }
    __syncthreads();
    u16* dbase; int c0;
    if (MODE == 4 && bn >= 512) { dbase = (u16*)Cv2; c0 = bn - 512; }
    else                        { dbase = (u16*)Cv;  c0 = bn; }
    #pragma unroll
    for (int q = 0; q < 8; q++) {
      int flat = q * 256 + tid;
      int row = flat >> 4, cv = flat & 15;
      *(uint4*)&dbase[(size_t)(bm + row) * 512 + c0 + cv * 8] =
          *(const uint4*)&eps[row * 136 + cv * 8];
    }
  }
}

// ------------- out_proj + residual + rmsnorm fused: 64x256 tile -------------
// h[M,256] += yz @ opW^T ; xn = f2b(h * rsqrt(mean h^2) * nw)
__global__ __launch_bounds__(256) void mgemm7_k(
    const u16* __restrict__ A,     // yz [M,512] bf16
    const u16* __restrict__ W,     // opW [256,512] bf16
    float* __restrict__ h,         // [M,256] f32 (residual in/out)
    const float* __restrict__ nw,  // next-layer norm weight [256]
    u16* __restrict__ xnb)         // [M,256] bf16
{
  __shared__ u16 smem[20480];      // A 4096 + B 16384 u16 ; epilogue: 64x264
  __shared__ float rns[2][64];
  __shared__ float snw[256];
  u16* sA = smem;
  u16* sB = smem + 4096;
  const int tid = threadIdx.x;
  const int bm = blockIdx.x * 64;
  const int w = tid >> 6, l = tid & 63;
  const int wm = (w & 1) * 32, wn = (w >> 1) * 128;
  const int lr = l & 15, lh = l >> 4;

  if (tid < 256) snw[tid] = nw[tid];

  f32x4 acc[2][8] = {};

  const int srow = tid >> 3;
  const int schunk = tid & 7;

  for (int k0 = 0; k0 < 512; k0 += 64) {
    #pragma unroll
    for (int c = 0; c < 2; c++) {
      int row = c * 32 + srow;
      int g = schunk ^ (row & 7);
      async16(A + (size_t)(bm + row) * 512 + k0 + g * 8, &sA[c * 2048 + w * 512]);
    }
    #pragma unroll
    for (int c = 0; c < 8; c++) {
      int row = c * 32 + srow;
      int g = schunk ^ (row & 7);
      async16(W + (size_t)row * 512 + k0 + g * 8, &sB[c * 2048 + w * 512]);
    }
    __syncthreads();
    #pragma unroll
    for (int kk = 0; kk < 2; kk++) {
      int e = kk * 4 + lh;
      bf16x8 af[2], bfr[8];
      #pragma unroll
      for (int i = 0; i < 2; i++) {
        int ra = wm + i * 16 + lr;
        af[i] = *(const bf16x8*)&sA[ra * 64 + ((e ^ (ra & 7)) * 8)];
      }
      #pragma unroll
      for (int j = 0; j < 8; j++) {
        int rb = wn + j * 16 + lr;
        bfr[j] = *(const bf16x8*)&sB[rb * 64 + ((e ^ (rb & 7)) * 8)];
      }
      #pragma unroll
      for (int i = 0; i < 2; i++)
        #pragma unroll
        for (int j = 0; j < 8; j++)
          acc[i][j] = __builtin_amdgcn_mfma_f32_16x16x32_bf16(af[i], bfr[j], acc[i][j], 0, 0, 0);
    }
    __syncthreads();
  }

  // residual add + h store; keep h_new in acc
  #pragma unroll
  for (int i = 0; i < 2; i++) {
    int m = bm + wm + i * 16 + lh * 4;
    #pragma unroll
    for (int j = 0; j < 8; j++) {
      int n = wn + j * 16 + lr;
      float* cp = h + (size_t)m * 256 + n;
      #pragma unroll
      for (int r = 0; r < 4; r++) {
        float hv = acc[i][j][r] + cp[(size_t)r * 256];
        cp[(size_t)r * 256] = hv;
        acc[i][j][r] = hv;
      }
    }
  }
  // per-row ssq: reduce over lr lanes, one writer per (wavecol,row)
  #pragma unroll
  for (int i = 0; i < 2; i++) {
    #pragma unroll
    for (int r = 0; r < 4; r++) {
      float p = 0.f;
      #pragma unroll
      for (int j = 0; j < 8; j++) { float v = acc[i][j][r]; p += v * v; }
      p += __shfl_xor(p, 1, 64);
      p += __shfl_xor(p, 2, 64);
      p += __shfl_xor(p, 4, 64);
      p += __shfl_xor(p, 8, 64);
      if (lr == 0) rns[w >> 1][wm + i * 16 + lh * 4 + r] = p;
    }
  }
  __syncthreads();
  // xn into LDS (64 x 264 u16)
  u16* eps = smem;
  #pragma unroll
  for (int i = 0; i < 2; i++) {
    #pragma unroll
    for (int r = 0; r < 4; r++) {
      int rl = wm + i * 16 + lh * 4 + r;
      float rs = rsqrtf((rns[0][rl] + rns[1][rl]) * (1.f / 256.f) + 1e-5f);
      #pragma unroll
      for (int j = 0; j < 8; j++) {
        int n = wn + j * 16 + lr;
        eps[rl * 264 + n] = f2b(acc[i][j][r] * rs * snw[n]);
      }
    }
  }
  __syncthreads();
  #pragma unroll
  for (int q = 0; q < 8; q++) {
    int flat = q * 256 + tid;
    int row = flat >> 5, cv = flat & 31;
    *(uint4*)&xnb[(size_t)(bm + row) * 256 + cv * 8] =
        *(const uint4*)&eps[row * 264 + cv * 8];
  }
}

// -------------------- causal depthwise conv + silu --------------------
__global__ __launch_bounds__(256) void conv_silu_k(
    const u16* __restrict__ xib,      // [B*T,512] bf16
    const float* __restrict__ cw,     // [512,4]
    const float* __restrict__ cb,     // [512]
    u16* __restrict__ xcb)            // [B*T,512] bf16
{
  int idx = blockIdx.x * 256 + threadIdx.x;
  int row = idx >> 6;
  int t = row & (T_ - 1);
  int d0 = (idx & 63) << 3;

  float acc[8];
  *(float4*)&acc[0] = *(const float4*)&cb[d0];
  *(float4*)&acc[4] = *(const float4*)&cb[d0 + 4];
  float wreg[8][4];
  #pragma unroll
  for (int j = 0; j < 8; j++)
    *(float4*)&wreg[j][0] = *(const float4*)&cw[(d0 + j) * 4];

  #pragma unroll
  for (int k = 0; k < 4; k++) {
    int tt = t + k - 3;
    if (tt >= 0) {
      bf16x8 v = *(const bf16x8*)&xib[(size_t)(row + k - 3) * 512 + d0];
      #pragma unroll
      for (int j = 0; j < 8; j++) acc[j] += wreg[j][k] * b2f((u16)v[j]);
    }
  }
  u16 o[8];
  #pragma unroll
  for (int j = 0; j < 8; j++) o[j] = f2b(silu_f(acc[j]));
  *(bf16x8*)&xcb[(size_t)row * 512 + d0] = *(const bf16x8*)o;
}

// -------------------- chunked selective scan --------------------
__global__ __launch_bounds__(512) void scan_passA_k(
    const u16* __restrict__ xcb,      // u bf16 [B*T,512]
    const u16* __restrict__ dtb,      // dt bf16 [B*T,512]
    const float* __restrict__ xdbc,   // [M,32]: B cols 0:16
    const float* __restrict__ a2t,    // [16][512]
    u16* __restrict__ chH, float* __restrict__ dts)
{
  __shared__ float sDBC[TC_ * 32];
  int c = blockIdx.x, b = blockIdx.y, d = threadIdx.x;
  size_t base_row = (size_t)(b * T_ + c * TC_);

  if (d < 128) async16(xdbc + base_row * 32 + d * 4, &sDBC[(d >> 6) * 256]);

  float a2[16], hl[16];
  #pragma unroll
  for (int n = 0; n < 16; n++) { a2[n] = a2t[n * 512 + d]; hl[n] = 0.f; }
  float dtsum = 0.f;
  const u16* up = xcb + base_row * 512 + d;
  const u16* tp = dtb + base_row * 512 + d;
  u16 pu = up[0], pt = tp[0];
  __syncthreads();

  #pragma unroll 1
  for (int s = 0; s < TC_; s++) {
    float u   = b2f(pu);
    float dtv = b2f(pt);
    int sn = (s + 1 < TC_) ? s + 1 : s;
    pu = up[(size_t)sn * 512];
    pt = tp[(size_t)sn * 512];
    dtsum += dtv;
    float du = dtv * u;
    const float* rowp = &sDBC[s * 32];
    #pragma unroll
    for (int g = 0; g < 4; g++) {
      float4 b4 = *(const float4*)&rowp[g * 4];
      int i = g * 4;
      float dA0 = exp2_i(dtv * a2[i + 0]); hl[i + 0] = dA0 * hl[i + 0] + du * b4.x;
      float dA1 = exp2_i(dtv * a2[i + 1]); hl[i + 1] = dA1 * hl[i + 1] + du * b4.y;
      float dA2 = exp2_i(dtv * a2[i + 2]); hl[i + 2] = dA2 * hl[i + 2] + du * b4.z;
      float dA3 = exp2_i(dtv * a2[i + 3]); hl[i + 3] = dA3 * hl[i + 3] + du * b4.w;
    }
  }
  u16 oh[16];
  #pragma unroll
  for (int n = 0; n < 16; n++) oh[n] = f2b(hl[n]);
  size_t o = ((size_t)((b * NC_ + c) * DIN_ + d)) * 16;
  *(uint4*)&chH[o]     = *(const uint4*)&oh[0];
  *(uint4*)&chH[o + 8] = *(const uint4*)&oh[8];
  dts[(size_t)(b * NC_ + c) * DIN_ + d] = dtsum;
}

__global__ __launch_bounds__(256) void scan_mid_k(
    const u32* __restrict__ chH32, const float* __restrict__ dts,
    const float* __restrict__ a2t, u32* __restrict__ hin32)
{
  int idx = blockIdx.x * 256 + threadIdx.x;   // B*DIN*8 = 32768
  int b = idx >> 12, dk = idx & 4095;
  int d = dk >> 3, k = dk & 7;
  float a20 = a2t[(2 * k) * 512 + d];
  float a21 = a2t[(2 * k + 1) * 512 + d];
  float h0 = 0.f, h1 = 0.f;
  #pragma unroll 8
  for (int c = 0; c < NC_; c++) {
    size_t o = ((size_t)(b * NC_ + c)) * 4096 + dk;
    u32 hh = chH32[o];
    float dsv = dts[(size_t)(b * NC_ + c) * 512 + d];
    hin32[o] = ((u32)f2b(h1) << 16) | (u32)f2b(h0);
    float ap0 = exp2_i(a20 * dsv);
    float ap1 = exp2_i(a21 * dsv);
    h0 = ap0 * h0 + b2f((u16)(hh & 0xffff));
    h1 = ap1 * h1 + b2f((u16)(hh >> 16));
  }
}

__global__ __launch_bounds__(512) void scan_passC_k(
    const u16* __restrict__ xcb,
    const u16* __restrict__ dtb,
    const u16* __restrict__ zb,
    const float* __restrict__ xdbc,   // [M,32]: B 0:16, C 16:32
    const float* __restrict__ a2t,
    const u16* __restrict__ hin,      // h_in bf16
    const float* __restrict__ Dv,
    u16* __restrict__ yzb)
{
  __shared__ float sDBC[TC_ * 32];
  int c = blockIdx.x, b = blockIdx.y, d = threadIdx.x;
  size_t base_row = (size_t)(b * T_ + c * TC_);

  if (d < 128) async16(xdbc + base_row * 32 + d * 4, &sDBC[(d >> 6) * 256]);

  float a2[16], hs[16];
  {
    size_t ho = ((size_t)((b * NC_ + c) * DIN_ + d)) * 16;
    uint4 h0 = *(const uint4*)&hin[ho];
    uint4 h1 = *(const uint4*)&hin[ho + 8];
    const u32* hw = (const u32*)&h0;
    #pragma unroll
    for (int j = 0; j < 4; j++) {
      hs[2 * j]     = b2f((u16)(hw[j] & 0xffff));
      hs[2 * j + 1] = b2f((u16)(hw[j] >> 16));
    }
    const u32* hw1 = (const u32*)&h1;
    #pragma unroll
    for (int j = 0; j < 4; j++) {
      hs[8 + 2 * j]     = b2f((u16)(hw1[j] & 0xffff));
      hs[8 + 2 * j + 1] = b2f((u16)(hw1[j] >> 16));
    }
  }
  #pragma unroll
  for (int n = 0; n < 16; n++) a2[n] = a2t[n * 512 + d];
  float dv = Dv[d];
  const u16* up = xcb + base_row * 512 + d;
  const u16* tp = dtb + base_row * 512 + d;
  const u16* zp = zb + base_row * 512 + d;
  u16 pu = up[0], pt = tp[0], zz = zp[0];
  __syncthreads();

  #pragma unroll 1
  for (int s = 0; s < TC_; s++) {
    float u   = b2f(pu);
    float dtv = b2f(pt);
    float z   = b2f(zz);
    int sn = (s + 1 < TC_) ? s + 1 : s;
    pu = up[(size_t)sn * 512];
    pt = tp[(size_t)sn * 512];
    zz = zp[(size_t)sn * 512];
    float du = dtv * u;
    float y = 0.f;
    const float* rowp = &sDBC[s * 32];
    #pragma unroll
    for (int g = 0; g < 4; g++) {
      float4 b4 = *(const float4*)&rowp[g * 4];
      float4 c4 = *(const float4*)&rowp[16 + g * 4];
      int i = g * 4;
      float dA0 = exp2_i(dtv * a2[i + 0]); hs[i + 0] = dA0 * hs[i + 0] + du * b4.x; y += hs[i + 0] * c4.x;
      float dA1 = exp2_i(dtv * a2[i + 1]); hs[i + 1] = dA1 * hs[i + 1] + du * b4.y; y += hs[i + 1] * c4.y;
      float dA2 = exp2_i(dtv * a2[i + 2]); hs[i + 2] = dA2 * hs[i + 2] + du * b4.z; y += hs[i + 2] * c4.z;
      float dA3 = exp2_i(dtv * a2[i + 3]); hs[i + 3] = dA3 * hs[i + 3] + du * b4.w; y += hs[i + 3] * c4.w;
    }
    y += u * dv;
    yzb[(base_row + s) * DIN_ + d] = f2b(y * silu_f(z));
  }
}

// -------------------- pooling + head --------------------
__global__ __launch_bounds__(256) void pool_partial_k(const u16* __restrict__ xn, float* __restrict__ poolP)
{
  int b = blockIdx.x, tc = blockIdx.y, j = threadIdx.x;
  float s = 0.f;
  int t0 = tc * 256;
  #pragma unroll 4
  for (int tt = 0; tt < 256; tt++)
    s += b2f(xn[((size_t)(b * T_ + t0 + tt)) * HID_ + j]);
  poolP[(b * 8 + tc) * HID_ + j] = s;
}

__global__ __launch_bounds__(256) void head_k(
    const float* __restrict__ poolP,
    const float* __restrict__ denW, const float* __restrict__ denb,
    const float* __restrict__ hdW, const float* __restrict__ hdb,
    float* __restrict__ out)
{
  int b = blockIdx.x, j = threadIdx.x;
  float p = 0.f;
  #pragma unroll
  for (int tc = 0; tc < 8; tc++) p += poolP[(b * 8 + tc) * HID_ + j];
  p *= (1.f / 2048.f);
  __shared__ float pl[256], zs[256];
  pl[j] = p;
  __syncthreads();
  float acc = denb[j];
  #pragma unroll 8
  for (int k = 0; k < 256; k++) acc += pl[k] * denW[j * 256 + k];
  zs[j] = fmaxf(acc, 0.f);
  __syncthreads();
  if (j < 2) {
    float o = hdb[j];
    for (int k = 0; k < 256; k++) o += zs[k] * hdW[j * 256 + k];
    out[b * 2 + j] = o;
  }
}

// -------------------- host --------------------
extern "C" void kernel_launch(void* const* d_in, const int* in_sizes, int n_in,
                              void* d_out, int out_size, void* d_ws, size_t ws_size,
                              hipStream_t stream)
{
  const float* tsd   = (const float*)d_in[0];
  const float* stat  = (const float*)d_in[1];
  const float* ta    = (const float*)d_in[2];
  const float* tsW   = (const float*)d_in[3];
  const float* tsb   = (const float*)d_in[4];
  const float* t2vw  = (const float*)d_in[5];
  const float* t2vb  = (const float*)d_in[6];
  const float* timeW = (const float*)d_in[7];
  const float* timeb = (const float*)d_in[8];
  const float* statW = (const float*)d_in[9];
  const float* statb = (const float*)d_in[10];
  const float* lng   = (const float*)d_in[11];
  const float* lnb   = (const float*)d_in[12];
  const float* normw = (const float*)d_in[13];
  const float* ipW   = (const float*)d_in[14];
  const float* convW = (const float*)d_in[15];
  const float* convb = (const float*)d_in[16];
  const float* xpW   = (const float*)d_in[17];
  const float* dpW   = (const float*)d_in[18];
  const float* dpb   = (const float*)d_in[19];
  const float* Alog  = (const float*)d_in[20];
  const float* Dsk   = (const float*)d_in[21];
  const float* opW   = (const float*)d_in[22];
  const float* normf = (const float*)d_in[23];
  const float* denW  = (const float*)d_in[24];
  const float* denb  = (const float*)d_in[25];
  const float* hdW   = (const float*)d_in[26];
  const float* hdb   = (const float*)d_in[27];
  float* out = (float*)d_out;

  float* ws = (float*)d_ws;
  float* h    = ws;  ws += (size_t)B_ * T_ * HID_;
  float* xdbc = ws;  ws += (size_t)B_ * T_ * 32;
  float* poolP= ws;  ws += (size_t)B_ * 8 * HID_;
  float* a2t  = ws;  ws += (size_t)NL_ * NST_ * DIN_;
  float* dts  = ws;  ws += (size_t)B_ * NC_ * DIN_;
  u16* chH    = (u16*)ws;  ws += (size_t)B_ * NC_ * DIN_ * NST_ / 2;
  u16* hin    = (u16*)ws;  ws += (size_t)B_ * NC_ * DIN_ * NST_ / 2;
  u16* dtb    = (u16*)ws;  ws += (size_t)B_ * T_ * DIN_ / 2;
  u16* xi_b   = (u16*)ws;  ws += (size_t)B_ * T_ * DIN_ / 2;
  u16* z_b    = (u16*)ws;  ws += (size_t)B_ * T_ * DIN_ / 2;
  u16* xn_b   = (u16*)ws;  ws += (size_t)B_ * T_ * HID_ / 2;
  u16* xcb    = (u16*)ws;  ws += (size_t)B_ * T_ * DIN_ / 2;
  u16* yz_b   = (u16*)ws;  ws += (size_t)B_ * T_ * DIN_ / 2;
  u16* wipb   = (u16*)ws;  ws += (size_t)NL_ * 1024 * HID_ / 2;
  u16* wopb   = (u16*)ws;  ws += (size_t)NL_ * HID_ * DIN_ / 2;
  u16* wcomb  = (u16*)ws;  ws += (size_t)NL_ * 640 * DIN_ / 2;

  const int ROWS = B_ * T_;   // 16384

  {
    int nip = NL_ * 1024 * HID_;
    int nop = NL_ * HID_ * DIN_;
    f2b_k<<<nip / 1024, 256, 0, stream>>>(ipW, wipb, nip);
    f2b_k<<<nop / 1024, 256, 0, stream>>>(opW, wopb, nop);
    a2t_k<<<NL_ * NST_ * DIN_ / 256, 256, 0, stream>>>(Alog, a2t);
    wmerge_k<<<dim3(640, NL_), 512, 0, stream>>>(dpW, xpW, wcomb);
  }

  embed_ln_k<<<512, 256, 0, stream>>>(tsd, stat, ta, tsW, tsb, t2vw, t2vb,
                                      timeW, timeb, statW, statb, lng, lnb,
                                      normw, h, xn_b);

  for (int i = 0; i < NL_; i++) {
    const u16* wipbi = wipb + (size_t)i * 1024 * HID_;
    const u16* wopbi = wopb + (size_t)i * HID_ * DIN_;
    const u16* wcombi = wcomb + (size_t)i * 640 * DIN_;
    const float* dpbi = dpb + (size_t)i * DIN_;
    const float* a2ti = a2t + (size_t)i * NST_ * DIN_;
    const float* nw_next = (i < NL_ - 1) ? (normw + (i + 1) * HID_) : normf;

    // in_proj: one launch, dual dest (xi cols 0:512, z cols 512:1024)
    mgemm_k<4><<<dim3(ROWS / 128, 8), 256, 0, stream>>>(
        xn_b, HID_, wipbi, HID_, xi_b, 512, HID_, nullptr, z_b);
    // conv + silu -> xcb bf16
    conv_silu_k<<<ROWS * 64 / 256, 256, 0, stream>>>(xi_b, convW + i * DIN_ * 4, convb + i * DIN_, xcb);
    // dt (merged weight, softplus fused) -> dtb; B/C -> xdbc
    mgemm_k<6><<<dim3(ROWS / 128, 5), 256, 0, stream>>>(
        xcb, DIN_, wcombi, DIN_, dtb, 512, DIN_, dpbi, xdbc);
    // chunked selective scan -> yz bf16
    scan_passA_k<<<dim3(NC_, B_), DIN_, 0, stream>>>(xcb, dtb, xdbc, a2ti, chH, dts);
    scan_mid_k<<<B_ * DIN_ * 8 / 256, 256, 0, stream>>>((const u32*)chH, dts, a2ti, (u32*)hin);
    scan_passC_k<<<dim3(NC_, B_), DIN_, 0, stream>>>(xcb, dtb, z_b, xdbc, a2ti, hin,
                                                     Dsk + i * DIN_, yz_b);
    // out_proj + residual + rmsnorm(next) -> h f32, xn_b bf16
    mgemm7_k<<<ROWS / 64, 256, 0, stream>>>(yz_b, wopbi, h, nw_next, xn_b);
  }

  pool_partial_k<<<dim3(B_, 8), 256, 0, stream>>>(xn_b, poolP);
  head_k<<<B_, 256, 0, stream>>>(poolP, denW, denb, hdW, hdb, out);
}

// Round 14
// 612.315 us; speedup vs baseline: 1.4128x; 1.1438x over previous
//
#include <hip/hip_runtime.h>
#include <math.h>

#define B_ 8
#define T_ 2048
#define HID_ 256
#define DIN_ 512
#define NST_ 16
#define RANK_ 16
#define NL_ 4
#define NC_ 128  // scan chunks
#define TC_ 16   // steps per chunk

typedef unsigned short u16;
typedef unsigned int u32;
typedef __attribute__((ext_vector_type(8))) short bf16x8;
typedef __attribute__((ext_vector_type(4))) float f32x4;

__device__ __forceinline__ float exp2_i(float x) {
  float r; asm("v_exp_f32 %0, %1" : "=v"(r) : "v"(x)); return r;
}
__device__ __forceinline__ float log2_i(float x) {
  float r; asm("v_log_f32 %0, %1" : "=v"(r) : "v"(x)); return r;
}
__device__ __forceinline__ float rcp_i(float x) {
  float r; asm("v_rcp_f32 %0, %1" : "=v"(r) : "v"(x)); return r;
}
#define LOG2E 1.44269504f
#define LN2   0.69314718f

__device__ __forceinline__ float silu_f(float x) {
  return x * rcp_i(1.f + exp2_i(-LOG2E * x));
}
__device__ __forceinline__ float softplus_f(float x) {
  return (x > 20.f) ? x : LN2 * log2_i(1.f + exp2_i(LOG2E * x));
}

__device__ __forceinline__ u16 f2b(float f) {
  union { float f; unsigned u; } v; v.f = f;
  unsigned r = (v.u + 0x7FFFu + ((v.u >> 16) & 1u)) >> 16;
  return (u16)r;
}
__device__ __forceinline__ float b2f(u16 b) {
  union { unsigned u; float f; } v; v.u = ((unsigned)b) << 16;
  return v.f;
}

__device__ __forceinline__ void async16(const void* g, const void* l) {
  __builtin_amdgcn_global_load_lds(
      (const __attribute__((address_space(1))) unsigned int*)g,
      (__attribute__((address_space(3))) unsigned int*)l, 16, 0, 0);
}

// -------------------- merged prep: f2b(ipW), f2b(opW), a2t --------------------
// blocks 0..1023: ipW (1,048,576 f32) ; 1024..1535: opW (524,288) ; 1536..1663: a2t
__global__ __launch_bounds__(256) void prep_k(
    const float* __restrict__ ipW, u16* __restrict__ wipb,
    const float* __restrict__ opW, u16* __restrict__ wopb,
    const float* __restrict__ Alog, float* __restrict__ a2t)
{
  int blk = blockIdx.x;
  if (blk < 1024) {
    int i = (blk * 256 + threadIdx.x) * 4;
    float4 v = *(const float4*)(ipW + i);
    wipb[i + 0] = f2b(v.x); wipb[i + 1] = f2b(v.y);
    wipb[i + 2] = f2b(v.z); wipb[i + 3] = f2b(v.w);
  } else if (blk < 1536) {
    int i = ((blk - 1024) * 256 + threadIdx.x) * 4;
    float4 v = *(const float4*)(opW + i);
    wopb[i + 0] = f2b(v.x); wopb[i + 1] = f2b(v.y);
    wopb[i + 2] = f2b(v.z); wopb[i + 3] = f2b(v.w);
  } else {
    int idx = (blk - 1536) * 256 + threadIdx.x;   // NL*16*512 = 32768
    int l = idx >> 13, nd = idx & 8191;
    int n = nd >> 9, d = nd & 511;
    float al = Alog[(size_t)l * 8192 + d * 16 + n];
    a2t[(size_t)l * 8192 + n * 512 + d] = -exp2_i(al * LOG2E) * LOG2E;
  }
}

// -------------------- combined dt+BC weight: wcomb[l][640][512] bf16
__global__ __launch_bounds__(512) void wmerge_k(
    const float* __restrict__ dpW,   // [NL,512,16]
    const float* __restrict__ xpW,   // [NL,48,512]
    u16* __restrict__ wcomb)         // [NL,640,512] bf16
{
  int n = blockIdx.x, l = blockIdx.y, k = threadIdx.x;
  const float* xp = xpW + (size_t)l * 48 * 512;
  float acc;
  if (n < 512) {
    const float* dp = dpW + ((size_t)l * 512 + n) * 16;
    acc = 0.f;
    #pragma unroll
    for (int r = 0; r < 16; r++) acc += dp[r] * xp[r * 512 + k];
  } else if (n < 544) {
    acc = xp[(size_t)(16 + n - 512) * 512 + k];
  } else {
    acc = 0.f;
  }
  wcomb[((size_t)l * 640 + n) * 512 + k] = f2b(acc);
}

// -------------------- embed + layernorm + rmsnorm(normw0) ------------------
__global__ __launch_bounds__(256) void embed_ln_k(
    const float* __restrict__ tsd, const float* __restrict__ stat, const float* __restrict__ ta,
    const float* __restrict__ tsW, const float* __restrict__ tsb,
    const float* __restrict__ t2vw, const float* __restrict__ t2vb,
    const float* __restrict__ timeW, const float* __restrict__ timeb,
    const float* __restrict__ statW, const float* __restrict__ statb,
    const float* __restrict__ lng, const float* __restrict__ lnb,
    const float* __restrict__ nw0,
    float* __restrict__ hout, u16* __restrict__ xnb)
{
  __shared__ float xts[37 * 32];
  __shared__ float tvs[32 * 32];
  __shared__ float outs[32 * 257];
  __shared__ float smu[32], srs[32], srs2[32];
  int blk = blockIdx.x;             // 512 blocks
  int b = blk >> 6, t0 = (blk & 63) * 32;
  int j = threadIdx.x;

  float wts[37], wtv[32], wst[8];
  #pragma unroll
  for (int m = 0; m < 37; m++) wts[m] = tsW[j * 37 + m];
  #pragma unroll
  for (int e = 0; e < 32; e++) wtv[e] = timeW[j * 32 + e];
  #pragma unroll
  for (int s = 0; s < 8; s++) wst[s] = statW[j * 8 + s];
  float biasj = tsb[j] + timeb[j] + statb[j];
  float lngj = lng[j], lnbj = lnb[j];
  float nw0j = nw0[j];
  float stq[8];
  #pragma unroll
  for (int s = 0; s < 8; s++) stq[s] = stat[b * 8 + s];

  for (int idx = j; idx < 37 * 32; idx += 256) {
    int m = idx >> 5, tt = idx & 31;
    xts[idx] = tsd[((size_t)b * 37 + m) * T_ + t0 + tt];
  }
  {
    int rr = j >> 5, ee = j & 31;
    #pragma unroll
    for (int rp = 0; rp < 4; rp++) {
      int r = rp * 8 + rr;
      float tav = ta[b * T_ + t0 + r];
      float tv = tav * t2vw[ee] + t2vb[ee];
      tvs[r * 32 + ee] = (ee == 0) ? tv : sinf(tv);
    }
  }
  __syncthreads();

  for (int r = 0; r < 32; r++) {
    float acc = biasj;
    #pragma unroll
    for (int m = 0; m < 37; m++) acc += xts[m * 32 + r] * wts[m];
    #pragma unroll
    for (int e = 0; e < 32; e++) acc += tvs[r * 32 + e] * wtv[e];
    #pragma unroll
    for (int s = 0; s < 8; s++) acc += stq[s] * wst[s];
    outs[r * 257 + j] = acc;
  }
  __syncthreads();
  {
    int r = j >> 3, q = j & 7;
    const float* po = &outs[r * 257 + q * 32];
    float s = 0.f, ss = 0.f;
    #pragma unroll
    for (int i = 0; i < 32; i++) { float v = po[i]; s += v; ss += v * v; }
    s += __shfl_down(s, 1, 64); ss += __shfl_down(ss, 1, 64);
    s += __shfl_down(s, 2, 64); ss += __shfl_down(ss, 2, 64);
    s += __shfl_down(s, 4, 64); ss += __shfl_down(ss, 4, 64);
    if (q == 0) {
      float mu = s * (1.f / 256.f);
      smu[r] = mu;
      srs[r] = rsqrtf(ss * (1.f / 256.f) - mu * mu + 1e-12f);
    }
  }
  __syncthreads();
  for (int r = 0; r < 32; r++) {
    float v = outs[r * 257 + j];
    float hv = (v - smu[r]) * srs[r] * lngj + lnbj;
    hout[((size_t)(b * T_ + t0 + r)) * HID_ + j] = hv;
    outs[r * 257 + j] = hv;
  }
  __syncthreads();
  {
    int r = j >> 3, q = j & 7;
    const float* po = &outs[r * 257 + q * 32];
    float ss = 0.f;
    #pragma unroll
    for (int i = 0; i < 32; i++) { float v = po[i]; ss += v * v; }
    ss += __shfl_down(ss, 1, 64);
    ss += __shfl_down(ss, 2, 64);
    ss += __shfl_down(ss, 4, 64);
    if (q == 0) srs2[r] = rsqrtf(ss * (1.f / 256.f) + 1e-5f);
  }
  __syncthreads();
  for (int r = 0; r < 32; r++) {
    xnb[((size_t)(b * T_ + t0 + r)) * HID_ + j] = f2b(outs[r * 257 + j] * srs2[r] * nw0j);
  }
}

// -------------------- bf16 MFMA GEMM 128x128: C[M,N] = A @ W^T --------------
// MODE 4: bf16 out via LDS epilogue, dual dest split at col 512 (in_proj)
// MODE 6: cols<512: softplus(acc+bias) -> bf16 dtb; cols 512:544: f32 -> Cv2
template <int MODE>
__global__ __launch_bounds__(256) void mgemm_k(
    const u16* __restrict__ A, int lda,
    const u16* __restrict__ W, int ldw,
    void* __restrict__ Cv, int ldc,
    int K,
    const float* __restrict__ bias,
    void* __restrict__ Cv2)
{
  __shared__ u16 smem[128 * 136];   // tiles (2x8192) / epilogue stage
  u16* sA = smem;
  u16* sB = smem + 128 * 64;
  const int tid = threadIdx.x;
  const int bm = blockIdx.x * 128, bn = blockIdx.y * 128;
  const int w = tid >> 6, l = tid & 63;
  const int wm = (w & 1) * 64, wn = (w >> 1) * 64;
  const int lr = l & 15, lh = l >> 4;

  f32x4 acc[4][4] = {};

  const int srow = tid >> 3;
  const int schunk = tid & 7;

  for (int k0 = 0; k0 < K; k0 += 64) {
    #pragma unroll
    for (int c = 0; c < 4; c++) {
      int row = c * 32 + srow;
      int g = schunk ^ (row & 7);
      async16(A + (size_t)(bm + row) * lda + k0 + g * 8, &sA[c * 2048 + w * 512]);
      async16(W + (size_t)(bn + row) * ldw + k0 + g * 8, &sB[c * 2048 + w * 512]);
    }
    __syncthreads();
    #pragma unroll
    for (int kk = 0; kk < 2; kk++) {
      bf16x8 af[4], bfr[4];
      #pragma unroll
      for (int i = 0; i < 4; i++) {
        int ra = wm + i * 16 + lr;
        int rb = wn + i * 16 + lr;
        int e = kk * 4 + lh;
        af[i]  = *(const bf16x8*)&sA[ra * 64 + ((e ^ (ra & 7)) * 8)];
        bfr[i] = *(const bf16x8*)&sB[rb * 64 + ((e ^ (rb & 7)) * 8)];
      }
      #pragma unroll
      for (int i = 0; i < 4; i++)
        #pragma unroll
        for (int j = 0; j < 4; j++)
          acc[i][j] = __builtin_amdgcn_mfma_f32_16x16x32_bf16(af[i], bfr[j], acc[i][j], 0, 0, 0);
    }
    __syncthreads();
  }

  if (MODE == 6 && bn >= 512) {
    #pragma unroll
    for (int i = 0; i < 4; i++) {
      int m = bm + wm + i * 16 + lh * 4;
      #pragma unroll
      for (int j = 0; j < 4; j++) {
        int n = bn + wn + j * 16 + lr;
        if (n < 544) {
          #pragma unroll
          for (int r = 0; r < 4; r++)
            ((float*)Cv2)[(size_t)(m + r) * 32 + (n - 512)] = acc[i][j][r];
        }
      }
    }
  } else {
    u16* eps = smem;                 // 128 x 136 u16
    float bv[4];
    if (MODE == 6) {
      #pragma unroll
      for (int j = 0; j < 4; j++) bv[j] = bias[bn + wn + j * 16 + lr];
    }
    #pragma unroll
    for (int i = 0; i < 4; i++) {
      int rr = wm + i * 16 + lh * 4;
      #pragma unroll
      for (int j = 0; j < 4; j++) {
        int cc = wn + j * 16 + lr;
        #pragma unroll
        for (int r = 0; r < 4; r++) {
          float v = acc[i][j][r];
          if (MODE == 6) v = softplus_f(v + bv[j]);
          eps[(rr + r) * 136 + cc] = f2b(v);
        }
      }
    }
    __syncthreads();
    u16* dbase; int c0;
    if (MODE == 4 && bn >= 512) { dbase = (u16*)Cv2; c0 = bn - 512; }
    else                        { dbase = (u16*)Cv;  c0 = bn; }
    #pragma unroll
    for (int q = 0; q < 8; q++) {
      int flat = q * 256 + tid;
      int row = flat >> 4, cv = flat & 15;
      *(uint4*)&dbase[(size_t)(bm + row) * 512 + c0 + cv * 8] =
          *(const uint4*)&eps[row * 136 + cv * 8];
    }
  }
}

// ------------- out_proj + residual + rmsnorm fused: 64x256 tile -------------
// LAST=0: h += yz@W^T (store), xn = f2b(h*rsqrt*nw) (store)
// LAST=1: h_new kept in regs only; pooled column sums atomicAdd'd to poolP
template <int LAST>
__global__ __launch_bounds__(256) void mgemm7_k(
    const u16* __restrict__ A,     // yz [M,512] bf16
    const u16* __restrict__ W,     // opW [256,512] bf16
    float* __restrict__ h,         // [M,256] f32 (residual in/out)
    const float* __restrict__ nw,  // norm weight [256]
    u16* __restrict__ xnb,         // [M,256] bf16
    float* __restrict__ poolP)     // [8,256] f32 (LAST only)
{
  __shared__ u16 smem[20480];      // A 4096 + B 16384 u16 ; epilogue: 64x264
  __shared__ float rns[2][64];
  __shared__ float snw[256];
  u16* sA = smem;
  u16* sB = smem + 4096;
  const int tid = threadIdx.x;
  const int bm = blockIdx.x * 64;
  const int w = tid >> 6, l = tid & 63;
  const int wm = (w & 1) * 32, wn = (w >> 1) * 128;
  const int lr = l & 15, lh = l >> 4;

  if (tid < 256) snw[tid] = nw[tid];

  f32x4 acc[2][8] = {};

  const int srow = tid >> 3;
  const int schunk = tid & 7;

  for (int k0 = 0; k0 < 512; k0 += 64) {
    #pragma unroll
    for (int c = 0; c < 2; c++) {
      int row = c * 32 + srow;
      int g = schunk ^ (row & 7);
      async16(A + (size_t)(bm + row) * 512 + k0 + g * 8, &sA[c * 2048 + w * 512]);
    }
    #pragma unroll
    for (int c = 0; c < 8; c++) {
      int row = c * 32 + srow;
      int g = schunk ^ (row & 7);
      async16(W + (size_t)row * 512 + k0 + g * 8, &sB[c * 2048 + w * 512]);
    }
    __syncthreads();
    #pragma unroll
    for (int kk = 0; kk < 2; kk++) {
      int e = kk * 4 + lh;
      bf16x8 af[2], bfr[8];
      #pragma unroll
      for (int i = 0; i < 2; i++) {
        int ra = wm + i * 16 + lr;
        af[i] = *(const bf16x8*)&sA[ra * 64 + ((e ^ (ra & 7)) * 8)];
      }
      #pragma unroll
      for (int j = 0; j < 8; j++) {
        int rb = wn + j * 16 + lr;
        bfr[j] = *(const bf16x8*)&sB[rb * 64 + ((e ^ (rb & 7)) * 8)];
      }
      #pragma unroll
      for (int i = 0; i < 2; i++)
        #pragma unroll
        for (int j = 0; j < 8; j++)
          acc[i][j] = __builtin_amdgcn_mfma_f32_16x16x32_bf16(af[i], bfr[j], acc[i][j], 0, 0, 0);
    }
    __syncthreads();
  }

  // residual add; store h unless LAST
  #pragma unroll
  for (int i = 0; i < 2; i++) {
    int m = bm + wm + i * 16 + lh * 4;
    #pragma unroll
    for (int j = 0; j < 8; j++) {
      int n = wn + j * 16 + lr;
      float* cp = h + (size_t)m * 256 + n;
      #pragma unroll
      for (int r = 0; r < 4; r++) {
        float hv = acc[i][j][r] + cp[(size_t)r * 256];
        if (!LAST) cp[(size_t)r * 256] = hv;
        acc[i][j][r] = hv;
      }
    }
  }
  // per-row ssq
  #pragma unroll
  for (int i = 0; i < 2; i++) {
    #pragma unroll
    for (int r = 0; r < 4; r++) {
      float p = 0.f;
      #pragma unroll
      for (int j = 0; j < 8; j++) { float v = acc[i][j][r]; p += v * v; }
      p += __shfl_xor(p, 1, 64);
      p += __shfl_xor(p, 2, 64);
      p += __shfl_xor(p, 4, 64);
      p += __shfl_xor(p, 8, 64);
      if (lr == 0) rns[w >> 1][wm + i * 16 + lh * 4 + r] = p;
    }
  }
  __syncthreads();
  if (LAST) {
    // pooled column partials -> atomicAdd
    int b = bm >> 11;
    #pragma unroll
    for (int j = 0; j < 8; j++) {
      int n = wn + j * 16 + lr;
      float colp = 0.f;
      #pragma unroll
      for (int i = 0; i < 2; i++) {
        #pragma unroll
        for (int r = 0; r < 4; r++) {
          int rl = wm + i * 16 + lh * 4 + r;
          float rs = rsqrtf((rns[0][rl] + rns[1][rl]) * (1.f / 256.f) + 1e-5f);
          colp += acc[i][j][r] * rs;
        }
      }
      atomicAdd(&poolP[b * 256 + n], colp * snw[n]);
    }
  } else {
    u16* eps = smem;
    #pragma unroll
    for (int i = 0; i < 2; i++) {
      #pragma unroll
      for (int r = 0; r < 4; r++) {
        int rl = wm + i * 16 + lh * 4 + r;
        float rs = rsqrtf((rns[0][rl] + rns[1][rl]) * (1.f / 256.f) + 1e-5f);
        #pragma unroll
        for (int j = 0; j < 8; j++) {
          int n = wn + j * 16 + lr;
          eps[rl * 264 + n] = f2b(acc[i][j][r] * rs * snw[n]);
        }
      }
    }
    __syncthreads();
    #pragma unroll
    for (int q = 0; q < 8; q++) {
      int flat = q * 256 + tid;
      int row = flat >> 5, cv = flat & 31;
      *(uint4*)&xnb[(size_t)(bm + row) * 256 + cv * 8] =
          *(const uint4*)&eps[row * 264 + cv * 8];
    }
  }
}

// -------------------- causal depthwise conv + silu (4 t/thread) --------------
__global__ __launch_bounds__(256) void conv_silu_k(
    const u16* __restrict__ xib,      // [B*T,512] bf16
    const float* __restrict__ cw,     // [512,4]
    const float* __restrict__ cb,     // [512]
    u16* __restrict__ xcb)            // [B*T,512] bf16
{
  int idx = blockIdx.x * 256 + threadIdx.x;   // ROWS/4 * 64 threads
  int row0 = (idx >> 6) * 4;
  int t0 = row0 & (T_ - 1);
  int d0 = (idx & 63) << 3;

  float wreg[8][4];
  #pragma unroll
  for (int j = 0; j < 8; j++)
    *(float4*)&wreg[j][0] = *(const float4*)&cw[(d0 + j) * 4];
  float4 cbl = *(const float4*)&cb[d0];
  float4 cbh = *(const float4*)&cb[d0 + 4];

  bf16x8 xv[7];
  #pragma unroll
  for (int r = 0; r < 7; r++) {
    int tt = t0 - 3 + r;
    if (tt >= 0) {
      xv[r] = *(const bf16x8*)&xib[(size_t)(row0 - 3 + r) * 512 + d0];
    } else {
      #pragma unroll
      for (int j = 0; j < 8; j++) xv[r][j] = 0;
    }
  }

  #pragma unroll
  for (int o = 0; o < 4; o++) {
    float acc[8];
    acc[0] = cbl.x; acc[1] = cbl.y; acc[2] = cbl.z; acc[3] = cbl.w;
    acc[4] = cbh.x; acc[5] = cbh.y; acc[6] = cbh.z; acc[7] = cbh.w;
    #pragma unroll
    for (int k = 0; k < 4; k++) {
      bf16x8 v = xv[o + k];
      #pragma unroll
      for (int j = 0; j < 8; j++) acc[j] += wreg[j][k] * b2f((u16)v[j]);
    }
    u16 ot[8];
    #pragma unroll
    for (int j = 0; j < 8; j++) ot[j] = f2b(silu_f(acc[j]));
    *(bf16x8*)&xcb[(size_t)(row0 + o) * 512 + d0] = *(const bf16x8*)ot;
  }
}

// -------------------- chunked selective scan --------------------
__global__ __launch_bounds__(512) void scan_passA_k(
    const u16* __restrict__ xcb,      // u bf16 [B*T,512]
    const u16* __restrict__ dtb,      // dt bf16 [B*T,512]
    const float* __restrict__ xdbc,   // [M,32]: B cols 0:16
    const float* __restrict__ a2t,    // [16][512]
    u16* __restrict__ chH, float* __restrict__ dts)
{
  __shared__ float sDBC[TC_ * 32];
  int c = blockIdx.x, b = blockIdx.y, d = threadIdx.x;
  size_t base_row = (size_t)(b * T_ + c * TC_);

  if (d < 128) async16(xdbc + base_row * 32 + d * 4, &sDBC[(d >> 6) * 256]);

  float a2[16], hl[16];
  #pragma unroll
  for (int n = 0; n < 16; n++) { a2[n] = a2t[n * 512 + d]; hl[n] = 0.f; }
  float dtsum = 0.f;
  const u16* up = xcb + base_row * 512 + d;
  const u16* tp = dtb + base_row * 512 + d;
  u16 pu = up[0], pt = tp[0];
  __syncthreads();

  #pragma unroll 1
  for (int s = 0; s < TC_; s++) {
    float u   = b2f(pu);
    float dtv = b2f(pt);
    int sn = (s + 1 < TC_) ? s + 1 : s;
    pu = up[(size_t)sn * 512];
    pt = tp[(size_t)sn * 512];
    dtsum += dtv;
    float du = dtv * u;
    const float* rowp = &sDBC[s * 32];
    #pragma unroll
    for (int g = 0; g < 4; g++) {
      float4 b4 = *(const float4*)&rowp[g * 4];
      int i = g * 4;
      float dA0 = exp2_i(dtv * a2[i + 0]); hl[i + 0] = dA0 * hl[i + 0] + du * b4.x;
      float dA1 = exp2_i(dtv * a2[i + 1]); hl[i + 1] = dA1 * hl[i + 1] + du * b4.y;
      float dA2 = exp2_i(dtv * a2[i + 2]); hl[i + 2] = dA2 * hl[i + 2] + du * b4.z;
      float dA3 = exp2_i(dtv * a2[i + 3]); hl[i + 3] = dA3 * hl[i + 3] + du * b4.w;
    }
  }
  u16 oh[16];
  #pragma unroll
  for (int n = 0; n < 16; n++) oh[n] = f2b(hl[n]);
  size_t o = ((size_t)((b * NC_ + c) * DIN_ + d)) * 16;
  *(uint4*)&chH[o]     = *(const uint4*)&oh[0];
  *(uint4*)&chH[o + 8] = *(const uint4*)&oh[8];
  dts[(size_t)(b * NC_ + c) * DIN_ + d] = dtsum;
}

__global__ __launch_bounds__(256) void scan_mid_k(
    const u32* __restrict__ chH32, const float* __restrict__ dts,
    const float* __restrict__ a2t, u32* __restrict__ hin32)
{
  int idx = blockIdx.x * 256 + threadIdx.x;   // B*DIN*8 = 32768
  int b = idx >> 12, dk = idx & 4095;
  int d = dk >> 3, k = dk & 7;
  float a20 = a2t[(2 * k) * 512 + d];
  float a21 = a2t[(2 * k + 1) * 512 + d];
  float h0 = 0.f, h1 = 0.f;
  #pragma unroll 8
  for (int c = 0; c < NC_; c++) {
    size_t o = ((size_t)(b * NC_ + c)) * 4096 + dk;
    u32 hh = chH32[o];
    float dsv = dts[(size_t)(b * NC_ + c) * 512 + d];
    hin32[o] = ((u32)f2b(h1) << 16) | (u32)f2b(h0);
    float ap0 = exp2_i(a20 * dsv);
    float ap1 = exp2_i(a21 * dsv);
    h0 = ap0 * h0 + b2f((u16)(hh & 0xffff));
    h1 = ap1 * h1 + b2f((u16)(hh >> 16));
  }
}

__global__ __launch_bounds__(512) void scan_passC_k(
    const u16* __restrict__ xcb,
    const u16* __restrict__ dtb,
    const u16* __restrict__ zb,
    const float* __restrict__ xdbc,   // [M,32]: B 0:16, C 16:32
    const float* __restrict__ a2t,
    const u16* __restrict__ hin,      // h_in bf16
    const float* __restrict__ Dv,
    u16* __restrict__ yzb)
{
  __shared__ float sDBC[TC_ * 32];
  int c = blockIdx.x, b = blockIdx.y, d = threadIdx.x;
  size_t base_row = (size_t)(b * T_ + c * TC_);

  if (d < 128) async16(xdbc + base_row * 32 + d * 4, &sDBC[(d >> 6) * 256]);

  float a2[16], hs[16];
  {
    size_t ho = ((size_t)((b * NC_ + c) * DIN_ + d)) * 16;
    uint4 h0 = *(const uint4*)&hin[ho];
    uint4 h1 = *(const uint4*)&hin[ho + 8];
    const u32* hw = (const u32*)&h0;
    #pragma unroll
    for (int j = 0; j < 4; j++) {
      hs[2 * j]     = b2f((u16)(hw[j] & 0xffff));
      hs[2 * j + 1] = b2f((u16)(hw[j] >> 16));
    }
    const u32* hw1 = (const u32*)&h1;
    #pragma unroll
    for (int j = 0; j < 4; j++) {
      hs[8 + 2 * j]     = b2f((u16)(hw1[j] & 0xffff));
      hs[8 + 2 * j + 1] = b2f((u16)(hw1[j] >> 16));
    }
  }
  #pragma unroll
  for (int n = 0; n < 16; n++) a2[n] = a2t[n * 512 + d];
  float dv = Dv[d];
  const u16* up = xcb + base_row * 512 + d;
  const u16* tp = dtb + base_row * 512 + d;
  const u16* zp = zb + base_row * 512 + d;
  u16 pu = up[0], pt = tp[0], zz = zp[0];
  __syncthreads();

  #pragma unroll 1
  for (int s = 0; s < TC_; s++) {
    float u   = b2f(pu);
    float dtv = b2f(pt);
    float z   = b2f(zz);
    int sn = (s + 1 < TC_) ? s + 1 : s;
    pu = up[(size_t)sn * 512];
    pt = tp[(size_t)sn * 512];
    zz = zp[(size_t)sn * 512];
    float du = dtv * u;
    float y = 0.f;
    const float* rowp = &sDBC[s * 32];
    #pragma unroll
    for (int g = 0; g < 4; g++) {
      float4 b4 = *(const float4*)&rowp[g * 4];
      float4 c4 = *(const float4*)&rowp[16 + g * 4];
      int i = g * 4;
      float dA0 = exp2_i(dtv * a2[i + 0]); hs[i + 0] = dA0 * hs[i + 0] + du * b4.x; y += hs[i + 0] * c4.x;
      float dA1 = exp2_i(dtv * a2[i + 1]); hs[i + 1] = dA1 * hs[i + 1] + du * b4.y; y += hs[i + 1] * c4.y;
      float dA2 = exp2_i(dtv * a2[i + 2]); hs[i + 2] = dA2 * hs[i + 2] + du * b4.z; y += hs[i + 2] * c4.z;
      float dA3 = exp2_i(dtv * a2[i + 3]); hs[i + 3] = dA3 * hs[i + 3] + du * b4.w; y += hs[i + 3] * c4.w;
    }
    y += u * dv;
    yzb[(base_row + s) * DIN_ + d] = f2b(y * silu_f(z));
  }
}

// -------------------- head --------------------
__global__ __launch_bounds__(256) void head_k(
    const float* __restrict__ poolP,
    const float* __restrict__ denW, const float* __restrict__ denb,
    const float* __restrict__ hdW, const float* __restrict__ hdb,
    float* __restrict__ out)
{
  int b = blockIdx.x, j = threadIdx.x;
  float p = poolP[b * 256 + j] * (1.f / 2048.f);
  __shared__ float pl[256], zs[256];
  pl[j] = p;
  __syncthreads();
  float acc = denb[j];
  #pragma unroll 8
  for (int k = 0; k < 256; k++) acc += pl[k] * denW[j * 256 + k];
  zs[j] = fmaxf(acc, 0.f);
  __syncthreads();
  if (j < 2) {
    float o = hdb[j];
    for (int k = 0; k < 256; k++) o += zs[k] * hdW[j * 256 + k];
    out[b * 2 + j] = o;
  }
}

// -------------------- host --------------------
extern "C" void kernel_launch(void* const* d_in, const int* in_sizes, int n_in,
                              void* d_out, int out_size, void* d_ws, size_t ws_size,
                              hipStream_t stream)
{
  const float* tsd   = (const float*)d_in[0];
  const float* stat  = (const float*)d_in[1];
  const float* ta    = (const float*)d_in[2];
  const float* tsW   = (const float*)d_in[3];
  const float* tsb   = (const float*)d_in[4];
  const float* t2vw  = (const float*)d_in[5];
  const float* t2vb  = (const float*)d_in[6];
  const float* timeW = (const float*)d_in[7];
  const float* timeb = (const float*)d_in[8];
  const float* statW = (const float*)d_in[9];
  const float* statb = (const float*)d_in[10];
  const float* lng   = (const float*)d_in[11];
  const float* lnb   = (const float*)d_in[12];
  const float* normw = (const float*)d_in[13];
  const float* ipW   = (const float*)d_in[14];
  const float* convW = (const float*)d_in[15];
  const float* convb = (const float*)d_in[16];
  const float* xpW   = (const float*)d_in[17];
  const float* dpW   = (const float*)d_in[18];
  const float* dpb   = (const float*)d_in[19];
  const float* Alog  = (const float*)d_in[20];
  const float* Dsk   = (const float*)d_in[21];
  const float* opW   = (const float*)d_in[22];
  const float* normf = (const float*)d_in[23];
  const float* denW  = (const float*)d_in[24];
  const float* denb  = (const float*)d_in[25];
  const float* hdW   = (const float*)d_in[26];
  const float* hdb   = (const float*)d_in[27];
  float* out = (float*)d_out;

  float* ws = (float*)d_ws;
  float* h    = ws;  ws += (size_t)B_ * T_ * HID_;
  float* xdbc = ws;  ws += (size_t)B_ * T_ * 32;
  float* poolP= ws;  ws += (size_t)B_ * HID_;
  float* a2t  = ws;  ws += (size_t)NL_ * NST_ * DIN_;
  float* dts  = ws;  ws += (size_t)B_ * NC_ * DIN_;
  u16* chH    = (u16*)ws;  ws += (size_t)B_ * NC_ * DIN_ * NST_ / 2;
  u16* hin    = (u16*)ws;  ws += (size_t)B_ * NC_ * DIN_ * NST_ / 2;
  u16* dtb    = (u16*)ws;  ws += (size_t)B_ * T_ * DIN_ / 2;
  u16* xi_b   = (u16*)ws;  ws += (size_t)B_ * T_ * DIN_ / 2;
  u16* z_b    = (u16*)ws;  ws += (size_t)B_ * T_ * DIN_ / 2;
  u16* xn_b   = (u16*)ws;  ws += (size_t)B_ * T_ * HID_ / 2;
  u16* xcb    = (u16*)ws;  ws += (size_t)B_ * T_ * DIN_ / 2;
  u16* yz_b   = (u16*)ws;  ws += (size_t)B_ * T_ * DIN_ / 2;
  u16* wipb   = (u16*)ws;  ws += (size_t)NL_ * 1024 * HID_ / 2;
  u16* wopb   = (u16*)ws;  ws += (size_t)NL_ * HID_ * DIN_ / 2;
  u16* wcomb  = (u16*)ws;  ws += (size_t)NL_ * 640 * DIN_ / 2;

  const int ROWS = B_ * T_;   // 16384

  hipMemsetAsync(poolP, 0, (size_t)B_ * HID_ * sizeof(float), stream);
  prep_k<<<1664, 256, 0, stream>>>(ipW, wipb, opW, wopb, Alog, a2t);
  wmerge_k<<<dim3(640, NL_), 512, 0, stream>>>(dpW, xpW, wcomb);

  embed_ln_k<<<512, 256, 0, stream>>>(tsd, stat, ta, tsW, tsb, t2vw, t2vb,
                                      timeW, timeb, statW, statb, lng, lnb,
                                      normw, h, xn_b);

  for (int i = 0; i < NL_; i++) {
    const u16* wipbi = wipb + (size_t)i * 1024 * HID_;
    const u16* wopbi = wopb + (size_t)i * HID_ * DIN_;
    const u16* wcombi = wcomb + (size_t)i * 640 * DIN_;
    const float* dpbi = dpb + (size_t)i * DIN_;
    const float* a2ti = a2t + (size_t)i * NST_ * DIN_;
    const float* nw_next = (i < NL_ - 1) ? (normw + (i + 1) * HID_) : normf;

    // in_proj: one launch, dual dest (xi cols 0:512, z cols 512:1024)
    mgemm_k<4><<<dim3(ROWS / 128, 8), 256, 0, stream>>>(
        xn_b, HID_, wipbi, HID_, xi_b, 512, HID_, nullptr, z_b);
    // conv + silu -> xcb bf16 (4 t/thread)
    conv_silu_k<<<ROWS * 16 / 256, 256, 0, stream>>>(xi_b, convW + i * DIN_ * 4, convb + i * DIN_, xcb);
    // dt (merged weight, softplus fused) -> dtb; B/C -> xdbc
    mgemm_k<6><<<dim3(ROWS / 128, 5), 256, 0, stream>>>(
        xcb, DIN_, wcombi, DIN_, dtb, 512, DIN_, dpbi, xdbc);
    // chunked selective scan -> yz bf16
    scan_passA_k<<<dim3(NC_, B_), DIN_, 0, stream>>>(xcb, dtb, xdbc, a2ti, chH, dts);
    scan_mid_k<<<B_ * DIN_ * 8 / 256, 256, 0, stream>>>((const u32*)chH, dts, a2ti, (u32*)hin);
    scan_passC_k<<<dim3(NC_, B_), DIN_, 0, stream>>>(xcb, dtb, z_b, xdbc, a2ti, hin,
                                                     Dsk + i * DIN_, yz_b);
    // out_proj + residual + rmsnorm(next) [+pool on last]
    if (i < NL_ - 1) {
      mgemm7_k<0><<<ROWS / 64, 256, 0, stream>>>(yz_b, wopbi, h, nw_next, xn_b, poolP);
    } else {
      mgemm7_k<1><<<ROWS / 64, 256, 0, stream>>>(yz_b, wopbi, h, nw_next, xn_b, poolP);
    }
  }

  head_k<<<B_, 256, 0, stream>>>(poolP, denW, denb, hdW, hdb, out);
}

// Round 15
// 578.792 us; speedup vs baseline: 1.4946x; 1.0579x over previous
//
#include <hip/hip_runtime.h>
#include <math.h>

#define B_ 8
#define T_ 2048
#define HID_ 256
#define DIN_ 512
#define NST_ 16
#define RANK_ 16
#define NL_ 4
#define NC_ 128  // scan chunks
#define TC_ 16   // steps per chunk

typedef unsigned short u16;
typedef unsigned int u32;
typedef __attribute__((ext_vector_type(8))) short bf16x8;
typedef __attribute__((ext_vector_type(4))) float f32x4;

__device__ __forceinline__ float exp2_i(float x) {
  float r; asm("v_exp_f32 %0, %1" : "=v"(r) : "v"(x)); return r;
}
__device__ __forceinline__ float log2_i(float x) {
  float r; asm("v_log_f32 %0, %1" : "=v"(r) : "v"(x)); return r;
}
__device__ __forceinline__ float rcp_i(float x) {
  float r; asm("v_rcp_f32 %0, %1" : "=v"(r) : "v"(x)); return r;
}
#define LOG2E 1.44269504f
#define LN2   0.69314718f

__device__ __forceinline__ float silu_f(float x) {
  return x * rcp_i(1.f + exp2_i(-LOG2E * x));
}
__device__ __forceinline__ float softplus_f(float x) {
  return (x > 20.f) ? x : LN2 * log2_i(1.f + exp2_i(LOG2E * x));
}

__device__ __forceinline__ u16 f2b(float f) {
  union { float f; unsigned u; } v; v.f = f;
  unsigned r = (v.u + 0x7FFFu + ((v.u >> 16) & 1u)) >> 16;
  return (u16)r;
}
__device__ __forceinline__ float b2f(u16 b) {
  union { unsigned u; float f; } v; v.u = ((unsigned)b) << 16;
  return v.f;
}

__device__ __forceinline__ void async16(const void* g, const void* l) {
  __builtin_amdgcn_global_load_lds(
      (const __attribute__((address_space(1))) unsigned int*)g,
      (__attribute__((address_space(3))) unsigned int*)l, 16, 0, 0);
}

// -------------------- merged prep: f2b(ipW), f2b(opW), a2t --------------------
__global__ __launch_bounds__(256) void prep_k(
    const float* __restrict__ ipW, u16* __restrict__ wipb,
    const float* __restrict__ opW, u16* __restrict__ wopb,
    const float* __restrict__ Alog, float* __restrict__ a2t)
{
  int blk = blockIdx.x;
  if (blk < 1024) {
    int i = (blk * 256 + threadIdx.x) * 4;
    float4 v = *(const float4*)(ipW + i);
    wipb[i + 0] = f2b(v.x); wipb[i + 1] = f2b(v.y);
    wipb[i + 2] = f2b(v.z); wipb[i + 3] = f2b(v.w);
  } else if (blk < 1536) {
    int i = ((blk - 1024) * 256 + threadIdx.x) * 4;
    float4 v = *(const float4*)(opW + i);
    wopb[i + 0] = f2b(v.x); wopb[i + 1] = f2b(v.y);
    wopb[i + 2] = f2b(v.z); wopb[i + 3] = f2b(v.w);
  } else {
    int idx = (blk - 1536) * 256 + threadIdx.x;   // NL*16*512 = 32768
    int l = idx >> 13, nd = idx & 8191;
    int n = nd >> 9, d = nd & 511;
    float al = Alog[(size_t)l * 8192 + d * 16 + n];
    a2t[(size_t)l * 8192 + n * 512 + d] = -exp2_i(al * LOG2E) * LOG2E;
  }
}

// -------------------- combined dt+BC weight: wcomb[l][640][512] bf16
__global__ __launch_bounds__(512) void wmerge_k(
    const float* __restrict__ dpW,   // [NL,512,16]
    const float* __restrict__ xpW,   // [NL,48,512]
    u16* __restrict__ wcomb)         // [NL,640,512] bf16
{
  int n = blockIdx.x, l = blockIdx.y, k = threadIdx.x;
  const float* xp = xpW + (size_t)l * 48 * 512;
  float acc;
  if (n < 512) {
    const float* dp = dpW + ((size_t)l * 512 + n) * 16;
    acc = 0.f;
    #pragma unroll
    for (int r = 0; r < 16; r++) acc += dp[r] * xp[r * 512 + k];
  } else if (n < 544) {
    acc = xp[(size_t)(16 + n - 512) * 512 + k];
  } else {
    acc = 0.f;
  }
  wcomb[((size_t)l * 640 + n) * 512 + k] = f2b(acc);
}

// -------------------- embed + layernorm + rmsnorm(normw0) ------------------
__global__ __launch_bounds__(256) void embed_ln_k(
    const float* __restrict__ tsd, const float* __restrict__ stat, const float* __restrict__ ta,
    const float* __restrict__ tsW, const float* __restrict__ tsb,
    const float* __restrict__ t2vw, const float* __restrict__ t2vb,
    const float* __restrict__ timeW, const float* __restrict__ timeb,
    const float* __restrict__ statW, const float* __restrict__ statb,
    const float* __restrict__ lng, const float* __restrict__ lnb,
    const float* __restrict__ nw0,
    float* __restrict__ hout, u16* __restrict__ xnb)
{
  __shared__ float xts[37 * 32];
  __shared__ float tvs[32 * 32];
  __shared__ float outs[32 * 257];
  __shared__ float smu[32], srs[32], srs2[32];
  int blk = blockIdx.x;             // 512 blocks
  int b = blk >> 6, t0 = (blk & 63) * 32;
  int j = threadIdx.x;

  float wts[37], wtv[32], wst[8];
  #pragma unroll
  for (int m = 0; m < 37; m++) wts[m] = tsW[j * 37 + m];
  #pragma unroll
  for (int e = 0; e < 32; e++) wtv[e] = timeW[j * 32 + e];
  #pragma unroll
  for (int s = 0; s < 8; s++) wst[s] = statW[j * 8 + s];
  float biasj = tsb[j] + timeb[j] + statb[j];
  float lngj = lng[j], lnbj = lnb[j];
  float nw0j = nw0[j];
  float stq[8];
  #pragma unroll
  for (int s = 0; s < 8; s++) stq[s] = stat[b * 8 + s];

  for (int idx = j; idx < 37 * 32; idx += 256) {
    int m = idx >> 5, tt = idx & 31;
    xts[idx] = tsd[((size_t)b * 37 + m) * T_ + t0 + tt];
  }
  {
    int rr = j >> 5, ee = j & 31;
    #pragma unroll
    for (int rp = 0; rp < 4; rp++) {
      int r = rp * 8 + rr;
      float tav = ta[b * T_ + t0 + r];
      float tv = tav * t2vw[ee] + t2vb[ee];
      tvs[r * 32 + ee] = (ee == 0) ? tv : sinf(tv);
    }
  }
  __syncthreads();

  for (int r = 0; r < 32; r++) {
    float acc = biasj;
    #pragma unroll
    for (int m = 0; m < 37; m++) acc += xts[m * 32 + r] * wts[m];
    #pragma unroll
    for (int e = 0; e < 32; e++) acc += tvs[r * 32 + e] * wtv[e];
    #pragma unroll
    for (int s = 0; s < 8; s++) acc += stq[s] * wst[s];
    outs[r * 257 + j] = acc;
  }
  __syncthreads();
  {
    int r = j >> 3, q = j & 7;
    const float* po = &outs[r * 257 + q * 32];
    float s = 0.f, ss = 0.f;
    #pragma unroll
    for (int i = 0; i < 32; i++) { float v = po[i]; s += v; ss += v * v; }
    s += __shfl_down(s, 1, 64); ss += __shfl_down(ss, 1, 64);
    s += __shfl_down(s, 2, 64); ss += __shfl_down(ss, 2, 64);
    s += __shfl_down(s, 4, 64); ss += __shfl_down(ss, 4, 64);
    if (q == 0) {
      float mu = s * (1.f / 256.f);
      smu[r] = mu;
      srs[r] = rsqrtf(ss * (1.f / 256.f) - mu * mu + 1e-12f);
    }
  }
  __syncthreads();
  for (int r = 0; r < 32; r++) {
    float v = outs[r * 257 + j];
    float hv = (v - smu[r]) * srs[r] * lngj + lnbj;
    hout[((size_t)(b * T_ + t0 + r)) * HID_ + j] = hv;
    outs[r * 257 + j] = hv;
  }
  __syncthreads();
  {
    int r = j >> 3, q = j & 7;
    const float* po = &outs[r * 257 + q * 32];
    float ss = 0.f;
    #pragma unroll
    for (int i = 0; i < 32; i++) { float v = po[i]; ss += v * v; }
    ss += __shfl_down(ss, 1, 64);
    ss += __shfl_down(ss, 2, 64);
    ss += __shfl_down(ss, 4, 64);
    if (q == 0) srs2[r] = rsqrtf(ss * (1.f / 256.f) + 1e-5f);
  }
  __syncthreads();
  for (int r = 0; r < 32; r++) {
    xnb[((size_t)(b * T_ + t0 + r)) * HID_ + j] = f2b(outs[r * 257 + j] * srs2[r] * nw0j);
  }
}

// -------------------- bf16 MFMA GEMM 128x128: C[M,N] = A @ W^T --------------
// MODE 4: bf16 out via LDS epilogue, dual dest split at col 512 (in_proj)
// MODE 6: cols<512: softplus(acc+bias) -> bf16 dtb; cols 512:544: f32 -> Cv2
template <int MODE>
__global__ __launch_bounds__(256) void mgemm_k(
    const u16* __restrict__ A, int lda,
    const u16* __restrict__ W, int ldw,
    void* __restrict__ Cv, int ldc,
    int K,
    const float* __restrict__ bias,
    void* __restrict__ Cv2)
{
  __shared__ u16 smem[128 * 136];   // tiles (2x8192) / epilogue stage
  u16* sA = smem;
  u16* sB = smem + 128 * 64;
  const int tid = threadIdx.x;
  const int bm = blockIdx.x * 128, bn = blockIdx.y * 128;
  const int w = tid >> 6, l = tid & 63;
  const int wm = (w & 1) * 64, wn = (w >> 1) * 64;
  const int lr = l & 15, lh = l >> 4;

  f32x4 acc[4][4] = {};

  const int srow = tid >> 3;
  const int schunk = tid & 7;

  for (int k0 = 0; k0 < K; k0 += 64) {
    #pragma unroll
    for (int c = 0; c < 4; c++) {
      int row = c * 32 + srow;
      int g = schunk ^ (row & 7);
      async16(A + (size_t)(bm + row) * lda + k0 + g * 8, &sA[c * 2048 + w * 512]);
      async16(W + (size_t)(bn + row) * ldw + k0 + g * 8, &sB[c * 2048 + w * 512]);
    }
    __syncthreads();
    #pragma unroll
    for (int kk = 0; kk < 2; kk++) {
      bf16x8 af[4], bfr[4];
      #pragma unroll
      for (int i = 0; i < 4; i++) {
        int ra = wm + i * 16 + lr;
        int rb = wn + i * 16 + lr;
        int e = kk * 4 + lh;
        af[i]  = *(const bf16x8*)&sA[ra * 64 + ((e ^ (ra & 7)) * 8)];
        bfr[i] = *(const bf16x8*)&sB[rb * 64 + ((e ^ (rb & 7)) * 8)];
      }
      #pragma unroll
      for (int i = 0; i < 4; i++)
        #pragma unroll
        for (int j = 0; j < 4; j++)
          acc[i][j] = __builtin_amdgcn_mfma_f32_16x16x32_bf16(af[i], bfr[j], acc[i][j], 0, 0, 0);
    }
    __syncthreads();
  }

  if (MODE == 6 && bn >= 512) {
    #pragma unroll
    for (int i = 0; i < 4; i++) {
      int m = bm + wm + i * 16 + lh * 4;
      #pragma unroll
      for (int j = 0; j < 4; j++) {
        int n = bn + wn + j * 16 + lr;
        if (n < 544) {
          #pragma unroll
          for (int r = 0; r < 4; r++)
            ((float*)Cv2)[(size_t)(m + r) * 32 + (n - 512)] = acc[i][j][r];
        }
      }
    }
  } else {
    u16* eps = smem;                 // 128 x 136 u16
    float bv[4];
    if (MODE == 6) {
      #pragma unroll
      for (int j = 0; j < 4; j++) bv[j] = bias[bn + wn + j * 16 + lr];
    }
    #pragma unroll
    for (int i = 0; i < 4; i++) {
      int rr = wm + i * 16 + lh * 4;
      #pragma unroll
      for (int j = 0; j < 4; j++) {
        int cc = wn + j * 16 + lr;
        #pragma unroll
        for (int r = 0; r < 4; r++) {
          float v = acc[i][j][r];
          if (MODE == 6) v = softplus_f(v + bv[j]);
          eps[(rr + r) * 136 + cc] = f2b(v);
        }
      }
    }
    __syncthreads();
    u16* dbase; int c0;
    if (MODE == 4 && bn >= 512) { dbase = (u16*)Cv2; c0 = bn - 512; }
    else                        { dbase = (u16*)Cv;  c0 = bn; }
    #pragma unroll
    for (int q = 0; q < 8; q++) {
      int flat = q * 256 + tid;
      int row = flat >> 4, cv = flat & 15;
      *(uint4*)&dbase[(size_t)(bm + row) * 512 + c0 + cv * 8] =
          *(const uint4*)&eps[row * 136 + cv * 8];
    }
  }
}

// ------------- out_proj + residual + rmsnorm fused: 64x256 tile -------------
// LAST=0: h += yz@W^T (store), xn = f2b(h*rsqrt*nw) (store)
// LAST=1: no h/xn store; per-block pooled column sums -> poolP2[blk][256]
template <int LAST>
__global__ __launch_bounds__(256) void mgemm7_k(
    const u16* __restrict__ A,     // yz [M,512] bf16
    const u16* __restrict__ W,     // opW [256,512] bf16
    float* __restrict__ h,         // [M,256] f32 (residual in/out)
    const float* __restrict__ nw,  // norm weight [256]
    u16* __restrict__ xnb,         // [M,256] bf16
    float* __restrict__ poolP2)    // [nblk,256] f32 (LAST only)
{
  __shared__ u16 smem[20480];      // A 4096 + B 16384 u16 ; epilogue: 64x264
  __shared__ float rns[2][64];
  __shared__ float snw[256];
  __shared__ float colsum[256];
  u16* sA = smem;
  u16* sB = smem + 4096;
  const int tid = threadIdx.x;
  const int bm = blockIdx.x * 64;
  const int w = tid >> 6, l = tid & 63;
  const int wm = (w & 1) * 32, wn = (w >> 1) * 128;
  const int lr = l & 15, lh = l >> 4;

  if (tid < 256) { snw[tid] = nw[tid]; if (LAST) colsum[tid] = 0.f; }

  f32x4 acc[2][8] = {};

  const int srow = tid >> 3;
  const int schunk = tid & 7;

  for (int k0 = 0; k0 < 512; k0 += 64) {
    #pragma unroll
    for (int c = 0; c < 2; c++) {
      int row = c * 32 + srow;
      int g = schunk ^ (row & 7);
      async16(A + (size_t)(bm + row) * 512 + k0 + g * 8, &sA[c * 2048 + w * 512]);
    }
    #pragma unroll
    for (int c = 0; c < 8; c++) {
      int row = c * 32 + srow;
      int g = schunk ^ (row & 7);
      async16(W + (size_t)row * 512 + k0 + g * 8, &sB[c * 2048 + w * 512]);
    }
    __syncthreads();
    #pragma unroll
    for (int kk = 0; kk < 2; kk++) {
      int e = kk * 4 + lh;
      bf16x8 af[2], bfr[8];
      #pragma unroll
      for (int i = 0; i < 2; i++) {
        int ra = wm + i * 16 + lr;
        af[i] = *(const bf16x8*)&sA[ra * 64 + ((e ^ (ra & 7)) * 8)];
      }
      #pragma unroll
      for (int j = 0; j < 8; j++) {
        int rb = wn + j * 16 + lr;
        bfr[j] = *(const bf16x8*)&sB[rb * 64 + ((e ^ (rb & 7)) * 8)];
      }
      #pragma unroll
      for (int i = 0; i < 2; i++)
        #pragma unroll
        for (int j = 0; j < 8; j++)
          acc[i][j] = __builtin_amdgcn_mfma_f32_16x16x32_bf16(af[i], bfr[j], acc[i][j], 0, 0, 0);
    }
    __syncthreads();
  }

  // residual add; store h unless LAST
  #pragma unroll
  for (int i = 0; i < 2; i++) {
    int m = bm + wm + i * 16 + lh * 4;
    #pragma unroll
    for (int j = 0; j < 8; j++) {
      int n = wn + j * 16 + lr;
      float* cp = h + (size_t)m * 256 + n;
      #pragma unroll
      for (int r = 0; r < 4; r++) {
        float hv = acc[i][j][r] + cp[(size_t)r * 256];
        if (!LAST) cp[(size_t)r * 256] = hv;
        acc[i][j][r] = hv;
      }
    }
  }
  // per-row ssq
  #pragma unroll
  for (int i = 0; i < 2; i++) {
    #pragma unroll
    for (int r = 0; r < 4; r++) {
      float p = 0.f;
      #pragma unroll
      for (int j = 0; j < 8; j++) { float v = acc[i][j][r]; p += v * v; }
      p += __shfl_xor(p, 1, 64);
      p += __shfl_xor(p, 2, 64);
      p += __shfl_xor(p, 4, 64);
      p += __shfl_xor(p, 8, 64);
      if (lr == 0) rns[w >> 1][wm + i * 16 + lh * 4 + r] = p;
    }
  }
  __syncthreads();
  if (LAST) {
    // per-block pooled column sums via LDS, then one coalesced store
    #pragma unroll
    for (int j = 0; j < 8; j++) {
      int n = wn + j * 16 + lr;
      float colp = 0.f;
      #pragma unroll
      for (int i = 0; i < 2; i++) {
        #pragma unroll
        for (int r = 0; r < 4; r++) {
          int rl = wm + i * 16 + lh * 4 + r;
          float rs = rsqrtf((rns[0][rl] + rns[1][rl]) * (1.f / 256.f) + 1e-5f);
          colp += acc[i][j][r] * rs;
        }
      }
      atomicAdd(&colsum[n], colp);   // LDS atomic, 8 contributors/col
    }
    __syncthreads();
    if (tid < 256)
      poolP2[(size_t)blockIdx.x * 256 + tid] = colsum[tid] * snw[tid];
  } else {
    u16* eps = smem;
    #pragma unroll
    for (int i = 0; i < 2; i++) {
      #pragma unroll
      for (int r = 0; r < 4; r++) {
        int rl = wm + i * 16 + lh * 4 + r;
        float rs = rsqrtf((rns[0][rl] + rns[1][rl]) * (1.f / 256.f) + 1e-5f);
        #pragma unroll
        for (int j = 0; j < 8; j++) {
          int n = wn + j * 16 + lr;
          eps[rl * 264 + n] = f2b(acc[i][j][r] * rs * snw[n]);
        }
      }
    }
    __syncthreads();
    #pragma unroll
    for (int q = 0; q < 8; q++) {
      int flat = q * 256 + tid;
      int row = flat >> 5, cv = flat & 31;
      *(uint4*)&xnb[(size_t)(bm + row) * 256 + cv * 8] =
          *(const uint4*)&eps[row * 264 + cv * 8];
    }
  }
}

// -------------------- causal depthwise conv + silu (4 t/thread) --------------
__global__ __launch_bounds__(256) void conv_silu_k(
    const u16* __restrict__ xib,      // [B*T,512] bf16
    const float* __restrict__ cw,     // [512,4]
    const float* __restrict__ cb,     // [512]
    u16* __restrict__ xcb)            // [B*T,512] bf16
{
  int idx = blockIdx.x * 256 + threadIdx.x;   // ROWS/4 * 64 threads
  int row0 = (idx >> 6) * 4;
  int t0 = row0 & (T_ - 1);
  int d0 = (idx & 63) << 3;

  float wreg[8][4];
  #pragma unroll
  for (int j = 0; j < 8; j++)
    *(float4*)&wreg[j][0] = *(const float4*)&cw[(d0 + j) * 4];
  float4 cbl = *(const float4*)&cb[d0];
  float4 cbh = *(const float4*)&cb[d0 + 4];

  bf16x8 xv[7];
  #pragma unroll
  for (int r = 0; r < 7; r++) {
    int tt = t0 - 3 + r;
    if (tt >= 0) {
      xv[r] = *(const bf16x8*)&xib[(size_t)(row0 - 3 + r) * 512 + d0];
    } else {
      #pragma unroll
      for (int j = 0; j < 8; j++) xv[r][j] = 0;
    }
  }

  #pragma unroll
  for (int o = 0; o < 4; o++) {
    float acc[8];
    acc[0] = cbl.x; acc[1] = cbl.y; acc[2] = cbl.z; acc[3] = cbl.w;
    acc[4] = cbh.x; acc[5] = cbh.y; acc[6] = cbh.z; acc[7] = cbh.w;
    #pragma unroll
    for (int k = 0; k < 4; k++) {
      bf16x8 v = xv[o + k];
      #pragma unroll
      for (int j = 0; j < 8; j++) acc[j] += wreg[j][k] * b2f((u16)v[j]);
    }
    u16 ot[8];
    #pragma unroll
    for (int j = 0; j < 8; j++) ot[j] = f2b(silu_f(acc[j]));
    *(bf16x8*)&xcb[(size_t)(row0 + o) * 512 + d0] = *(const bf16x8*)ot;
  }
}

// -------------------- chunked selective scan --------------------
__global__ __launch_bounds__(512) void scan_passA_k(
    const u16* __restrict__ xcb,      // u bf16 [B*T,512]
    const u16* __restrict__ dtb,      // dt bf16 [B*T,512]
    const float* __restrict__ xdbc,   // [M,32]: B cols 0:16
    const float* __restrict__ a2t,    // [16][512]
    u16* __restrict__ chH, float* __restrict__ dts)
{
  __shared__ float sDBC[TC_ * 32];
  int c = blockIdx.x, b = blockIdx.y, d = threadIdx.x;
  size_t base_row = (size_t)(b * T_ + c * TC_);

  if (d < 128) async16(xdbc + base_row * 32 + d * 4, &sDBC[(d >> 6) * 256]);

  float a2[16], hl[16];
  #pragma unroll
  for (int n = 0; n < 16; n++) { a2[n] = a2t[n * 512 + d]; hl[n] = 0.f; }
  float dtsum = 0.f;
  const u16* up = xcb + base_row * 512 + d;
  const u16* tp = dtb + base_row * 512 + d;
  u16 pu = up[0], pt = tp[0];
  __syncthreads();

  #pragma unroll 1
  for (int s = 0; s < TC_; s++) {
    float u   = b2f(pu);
    float dtv = b2f(pt);
    int sn = (s + 1 < TC_) ? s + 1 : s;
    pu = up[(size_t)sn * 512];
    pt = tp[(size_t)sn * 512];
    dtsum += dtv;
    float du = dtv * u;
    const float* rowp = &sDBC[s * 32];
    #pragma unroll
    for (int g = 0; g < 4; g++) {
      float4 b4 = *(const float4*)&rowp[g * 4];
      int i = g * 4;
      float dA0 = exp2_i(dtv * a2[i + 0]); hl[i + 0] = dA0 * hl[i + 0] + du * b4.x;
      float dA1 = exp2_i(dtv * a2[i + 1]); hl[i + 1] = dA1 * hl[i + 1] + du * b4.y;
      float dA2 = exp2_i(dtv * a2[i + 2]); hl[i + 2] = dA2 * hl[i + 2] + du * b4.z;
      float dA3 = exp2_i(dtv * a2[i + 3]); hl[i + 3] = dA3 * hl[i + 3] + du * b4.w;
    }
  }
  u16 oh[16];
  #pragma unroll
  for (int n = 0; n < 16; n++) oh[n] = f2b(hl[n]);
  size_t o = ((size_t)((b * NC_ + c) * DIN_ + d)) * 16;
  *(uint4*)&chH[o]     = *(const uint4*)&oh[0];
  *(uint4*)&chH[o + 8] = *(const uint4*)&oh[8];
  dts[(size_t)(b * NC_ + c) * DIN_ + d] = dtsum;
}

__global__ __launch_bounds__(256) void scan_mid_k(
    const u32* __restrict__ chH32, const float* __restrict__ dts,
    const float* __restrict__ a2t, u32* __restrict__ hin32)
{
  int idx = blockIdx.x * 256 + threadIdx.x;   // B*DIN*8 = 32768
  int b = idx >> 12, dk = idx & 4095;
  int d = dk >> 3, k = dk & 7;
  float a20 = a2t[(2 * k) * 512 + d];
  float a21 = a2t[(2 * k + 1) * 512 + d];
  float h0 = 0.f, h1 = 0.f;
  #pragma unroll 8
  for (int c = 0; c < NC_; c++) {
    size_t o = ((size_t)(b * NC_ + c)) * 4096 + dk;
    u32 hh = chH32[o];
    float dsv = dts[(size_t)(b * NC_ + c) * 512 + d];
    hin32[o] = ((u32)f2b(h1) << 16) | (u32)f2b(h0);
    float ap0 = exp2_i(a20 * dsv);
    float ap1 = exp2_i(a21 * dsv);
    h0 = ap0 * h0 + b2f((u16)(hh & 0xffff));
    h1 = ap1 * h1 + b2f((u16)(hh >> 16));
  }
}

__global__ __launch_bounds__(512) void scan_passC_k(
    const u16* __restrict__ xcb,
    const u16* __restrict__ dtb,
    const u16* __restrict__ zb,
    const float* __restrict__ xdbc,   // [M,32]: B 0:16, C 16:32
    const float* __restrict__ a2t,
    const u16* __restrict__ hin,      // h_in bf16
    const float* __restrict__ Dv,
    u16* __restrict__ yzb)
{
  __shared__ float sDBC[TC_ * 32];
  int c = blockIdx.x, b = blockIdx.y, d = threadIdx.x;
  size_t base_row = (size_t)(b * T_ + c * TC_);

  if (d < 128) async16(xdbc + base_row * 32 + d * 4, &sDBC[(d >> 6) * 256]);

  float a2[16], hs[16];
  {
    size_t ho = ((size_t)((b * NC_ + c) * DIN_ + d)) * 16;
    uint4 h0 = *(const uint4*)&hin[ho];
    uint4 h1 = *(const uint4*)&hin[ho + 8];
    const u32* hw = (const u32*)&h0;
    #pragma unroll
    for (int j = 0; j < 4; j++) {
      hs[2 * j]     = b2f((u16)(hw[j] & 0xffff));
      hs[2 * j + 1] = b2f((u16)(hw[j] >> 16));
    }
    const u32* hw1 = (const u32*)&h1;
    #pragma unroll
    for (int j = 0; j < 4; j++) {
      hs[8 + 2 * j]     = b2f((u16)(hw1[j] & 0xffff));
      hs[8 + 2 * j + 1] = b2f((u16)(hw1[j] >> 16));
    }
  }
  #pragma unroll
  for (int n = 0; n < 16; n++) a2[n] = a2t[n * 512 + d];
  float dv = Dv[d];
  const u16* up = xcb + base_row * 512 + d;
  const u16* tp = dtb + base_row * 512 + d;
  const u16* zp = zb + base_row * 512 + d;
  u16 pu = up[0], pt = tp[0], zz = zp[0];
  __syncthreads();

  #pragma unroll 1
  for (int s = 0; s < TC_; s++) {
    float u   = b2f(pu);
    float dtv = b2f(pt);
    float z   = b2f(zz);
    int sn = (s + 1 < TC_) ? s + 1 : s;
    pu = up[(size_t)sn * 512];
    pt = tp[(size_t)sn * 512];
    zz = zp[(size_t)sn * 512];
    float du = dtv * u;
    float y = 0.f;
    const float* rowp = &sDBC[s * 32];
    #pragma unroll
    for (int g = 0; g < 4; g++) {
      float4 b4 = *(const float4*)&rowp[g * 4];
      float4 c4 = *(const float4*)&rowp[16 + g * 4];
      int i = g * 4;
      float dA0 = exp2_i(dtv * a2[i + 0]); hs[i + 0] = dA0 * hs[i + 0] + du * b4.x; y += hs[i + 0] * c4.x;
      float dA1 = exp2_i(dtv * a2[i + 1]); hs[i + 1] = dA1 * hs[i + 1] + du * b4.y; y += hs[i + 1] * c4.y;
      float dA2 = exp2_i(dtv * a2[i + 2]); hs[i + 2] = dA2 * hs[i + 2] + du * b4.z; y += hs[i + 2] * c4.z;
      float dA3 = exp2_i(dtv * a2[i + 3]); hs[i + 3] = dA3 * hs[i + 3] + du * b4.w; y += hs[i + 3] * c4.w;
    }
    y += u * dv;
    yzb[(base_row + s) * DIN_ + d] = f2b(y * silu_f(z));
  }
}

// -------------------- head --------------------
__global__ __launch_bounds__(256) void head_k(
    const float* __restrict__ poolP2,  // [256,256] per-block partials
    const float* __restrict__ denW, const float* __restrict__ denb,
    const float* __restrict__ hdW, const float* __restrict__ hdb,
    float* __restrict__ out)
{
  int b = blockIdx.x, j = threadIdx.x;
  float p = 0.f;
  #pragma unroll 4
  for (int q = 0; q < 32; q++)
    p += poolP2[(size_t)(b * 32 + q) * 256 + j];
  p *= (1.f / 2048.f);
  __shared__ float pl[256], zs[256];
  pl[j] = p;
  __syncthreads();
  float acc = denb[j];
  #pragma unroll 8
  for (int k = 0; k < 256; k++) acc += pl[k] * denW[j * 256 + k];
  zs[j] = fmaxf(acc, 0.f);
  __syncthreads();
  if (j < 2) {
    float o = hdb[j];
    for (int k = 0; k < 256; k++) o += zs[k] * hdW[j * 256 + k];
    out[b * 2 + j] = o;
  }
}

// -------------------- host --------------------
extern "C" void kernel_launch(void* const* d_in, const int* in_sizes, int n_in,
                              void* d_out, int out_size, void* d_ws, size_t ws_size,
                              hipStream_t stream)
{
  const float* tsd   = (const float*)d_in[0];
  const float* stat  = (const float*)d_in[1];
  const float* ta    = (const float*)d_in[2];
  const float* tsW   = (const float*)d_in[3];
  const float* tsb   = (const float*)d_in[4];
  const float* t2vw  = (const float*)d_in[5];
  const float* t2vb  = (const float*)d_in[6];
  const float* timeW = (const float*)d_in[7];
  const float* timeb = (const float*)d_in[8];
  const float* statW = (const float*)d_in[9];
  const float* statb = (const float*)d_in[10];
  const float* lng   = (const float*)d_in[11];
  const float* lnb   = (const float*)d_in[12];
  const float* normw = (const float*)d_in[13];
  const float* ipW   = (const float*)d_in[14];
  const float* convW = (const float*)d_in[15];
  const float* convb = (const float*)d_in[16];
  const float* xpW   = (const float*)d_in[17];
  const float* dpW   = (const float*)d_in[18];
  const float* dpb   = (const float*)d_in[19];
  const float* Alog  = (const float*)d_in[20];
  const float* Dsk   = (const float*)d_in[21];
  const float* opW   = (const float*)d_in[22];
  const float* normf = (const float*)d_in[23];
  const float* denW  = (const float*)d_in[24];
  const float* denb  = (const float*)d_in[25];
  const float* hdW   = (const float*)d_in[26];
  const float* hdb   = (const float*)d_in[27];
  float* out = (float*)d_out;

  float* ws = (float*)d_ws;
  float* h    = ws;  ws += (size_t)B_ * T_ * HID_;
  float* xdbc = ws;  ws += (size_t)B_ * T_ * 32;
  float* poolP2 = ws;  ws += (size_t)256 * HID_;      // per-block partials
  float* a2t  = ws;  ws += (size_t)NL_ * NST_ * DIN_;
  float* dts  = ws;  ws += (size_t)B_ * NC_ * DIN_;
  u16* chH    = (u16*)ws;  ws += (size_t)B_ * NC_ * DIN_ * NST_ / 2;
  u16* hin    = (u16*)ws;  ws += (size_t)B_ * NC_ * DIN_ * NST_ / 2;
  u16* dtb    = (u16*)ws;  ws += (size_t)B_ * T_ * DIN_ / 2;
  u16* xi_b   = (u16*)ws;  ws += (size_t)B_ * T_ * DIN_ / 2;
  u16* z_b    = (u16*)ws;  ws += (size_t)B_ * T_ * DIN_ / 2;
  u16* xn_b   = (u16*)ws;  ws += (size_t)B_ * T_ * HID_ / 2;
  u16* xcb    = (u16*)ws;  ws += (size_t)B_ * T_ * DIN_ / 2;
  u16* yz_b   = (u16*)ws;  ws += (size_t)B_ * T_ * DIN_ / 2;
  u16* wipb   = (u16*)ws;  ws += (size_t)NL_ * 1024 * HID_ / 2;
  u16* wopb   = (u16*)ws;  ws += (size_t)NL_ * HID_ * DIN_ / 2;
  u16* wcomb  = (u16*)ws;  ws += (size_t)NL_ * 640 * DIN_ / 2;

  const int ROWS = B_ * T_;   // 16384

  prep_k<<<1664, 256, 0, stream>>>(ipW, wipb, opW, wopb, Alog, a2t);
  wmerge_k<<<dim3(640, NL_), 512, 0, stream>>>(dpW, xpW, wcomb);

  embed_ln_k<<<512, 256, 0, stream>>>(tsd, stat, ta, tsW, tsb, t2vw, t2vb,
                                      timeW, timeb, statW, statb, lng, lnb,
                                      normw, h, xn_b);

  for (int i = 0; i < NL_; i++) {
    const u16* wipbi = wipb + (size_t)i * 1024 * HID_;
    const u16* wopbi = wopb + (size_t)i * HID_ * DIN_;
    const u16* wcombi = wcomb + (size_t)i * 640 * DIN_;
    const float* dpbi = dpb + (size_t)i * DIN_;
    const float* a2ti = a2t + (size_t)i * NST_ * DIN_;
    const float* nw_next = (i < NL_ - 1) ? (normw + (i + 1) * HID_) : normf;

    // in_proj: one launch, dual dest (xi cols 0:512, z cols 512:1024)
    mgemm_k<4><<<dim3(ROWS / 128, 8), 256, 0, stream>>>(
        xn_b, HID_, wipbi, HID_, xi_b, 512, HID_, nullptr, z_b);
    // conv + silu -> xcb bf16 (4 t/thread)
    conv_silu_k<<<ROWS * 16 / 256, 256, 0, stream>>>(xi_b, convW + i * DIN_ * 4, convb + i * DIN_, xcb);
    // dt (merged weight, softplus fused) -> dtb; B/C -> xdbc
    mgemm_k<6><<<dim3(ROWS / 128, 5), 256, 0, stream>>>(
        xcb, DIN_, wcombi, DIN_, dtb, 512, DIN_, dpbi, xdbc);
    // chunked selective scan -> yz bf16
    scan_passA_k<<<dim3(NC_, B_), DIN_, 0, stream>>>(xcb, dtb, xdbc, a2ti, chH, dts);
    scan_mid_k<<<B_ * DIN_ * 8 / 256, 256, 0, stream>>>((const u32*)chH, dts, a2ti, (u32*)hin);
    scan_passC_k<<<dim3(NC_, B_), DIN_, 0, stream>>>(xcb, dtb, z_b, xdbc, a2ti, hin,
                                                     Dsk + i * DIN_, yz_b);
    // out_proj + residual + rmsnorm(next) [+pool partials on last]
    if (i < NL_ - 1) {
      mgemm7_k<0><<<ROWS / 64, 256, 0, stream>>>(yz_b, wopbi, h, nw_next, xn_b, poolP2);
    } else {
      mgemm7_k<1><<<ROWS / 64, 256, 0, stream>>>(yz_b, wopbi, h, nw_next, xn_b, poolP2);
    }
  }

  head_k<<<B_, 256, 0, stream>>>(poolP2, denW, denb, hdW, hdb, out);
}